// Round 3
// baseline (656.908 us; speedup 1.0000x reference)
//
#include <hip/hip_runtime.h>
#include <hip/hip_bf16.h>
#include <hip/hip_cooperative_groups.h>

namespace cg = cooperative_groups;

#define BATCH 128
#define SGRID 32
#define NCELL 1024
#define NTOT  1025
#define FD    128
#define NACT  19
#define NEG_INF_F  (-3.4028234663852886e38f)  // jnp.finfo(float32).min
#define BF16_SAFE_F (3.3e38f)                 // < bf16 max finite (3.3895e38)
#define XSTR 136                              // LDS row stride (bf16); 272B keeps b128 align

typedef unsigned short ushort_t;
typedef unsigned int   uint_t;
typedef short   short8   __attribute__((ext_vector_type(8)));
typedef float   floatx16 __attribute__((ext_vector_type(16)));

__device__ __forceinline__ float elu_fast(float v) {   // bf16-accurate ELU
    return v > 0.f ? v : (__expf(v) - 1.f);
}
__device__ __forceinline__ float bf2f(ushort_t h) {
    union { uint_t u; float f; } v; v.u = ((uint_t)h) << 16; return v.f;
}
__device__ __forceinline__ ushort_t f2bf(float f) {   // round-to-nearest-even
    union { float f; uint_t u; } v; v.f = f;
    uint_t r = v.u + 0x7FFFu + ((v.u >> 16) & 1u);
    return (ushort_t)(r >> 16);
}
__device__ __forceinline__ uint_t pkbf(float a, float b) {  // v_cvt_pk_bf16_f32
    union { __hip_bfloat162 h; uint_t u; } v;
    v.h = __float22bfloat162_rn(make_float2(a, b));
    return v.u;
}
__device__ __forceinline__ void unpack2(uint_t u, float& a, float& b) {
    union { uint_t x; float f; } lo, hi;
    lo.x = u << 16; hi.x = u & 0xFFFF0000u;
    a = lo.f; b = hi.f;
}
__device__ __forceinline__ void unpack8(uint4 v, float* f) {
    unpack2(v.x, f[0], f[1]); unpack2(v.y, f[2], f[3]);
    unpack2(v.z, f[4], f[5]); unpack2(v.w, f[6], f[7]);
}
__device__ __forceinline__ void unpack4(uint2 v, float* f) {
    unpack2(v.x, f[0], f[1]); unpack2(v.y, f[2], f[3]);
}

// ---------------------------------------------------------------------------
// One R0-style GNN task (2-row tile, 256 threads, 34.8 KB LDS).
// tau in [0, 17*BATCH): tau&7 = XCD class (gridDim % 8 == 0 keeps
// blockIdx&7 == tau&7 under grid-stride), preserving L2 locality per layer.
// ---------------------------------------------------------------------------
__device__ void gnn_task(
    int tau, int t,
    const ushort_t* __restrict__ xprev, ushort_t* __restrict__ xnext,
    const ushort_t* __restrict__ wf,          // this layer's MFMA B-fragments
    const ushort_t* __restrict__ Wsl, const ushort_t* __restrict__ Wnl,
    const ushort_t* __restrict__ bsl,
    int meta_valid, int in_bstride,
    ushort_t* xt, ushort_t* at)
{
    const int xcd = tau & 7;
    const int j = tau >> 3;                    // 0..271
    const int b = xcd * 16 + j / 17;
    const int rb = j % 17;
    const ushort_t* xb = xprev + (size_t)b * in_bstride;
    ushort_t* yb = xnext + (size_t)b * (NTOT * FD);

    if (rb == 16) {
        // ---- meta node: reduce 1024 cells, then 1x128 GEMM ----
        float* part = (float*)xt;              // 16 x 128 floats (8 KB)
        float* msum = (float*)at;
        float* xm   = (float*)at + FD;
        const int kc = (t & 15) * 8;
        const int cg_ = t >> 4;                // 0..15
        float s[8];
        #pragma unroll
        for (int q = 0; q < 8; ++q) s[q] = 0.f;
        #pragma unroll 4
        for (int n = 0; n < 64; ++n) {
            const int cell = cg_ * 64 + n;
            float f[8]; unpack8(*(const uint4*)(xb + (size_t)cell * FD + kc), f);
            #pragma unroll
            for (int q = 0; q < 8; ++q) s[q] += f[q];
        }
        #pragma unroll
        for (int q = 0; q < 8; ++q) part[cg_ * FD + kc + q] = s[q];
        __syncthreads();
        if (t < FD) {
            float a = 0.f;
            #pragma unroll
            for (int gI = 0; gI < 16; ++gI) a += part[gI * FD + t];
            msum[t] = a;
            xm[t] = meta_valid ? bf2f(xb[(size_t)NCELL * FD + t]) : 0.f;
        }
        __syncthreads();
        if (t < FD) {
            float a = bf2f(bsl[t]);
            #pragma unroll 4
            for (int kk = 0; kk < FD; ++kk)
                a += xm[kk] * bf2f(Wsl[kk * FD + t]) + msum[kk] * bf2f(Wnl[kk * FD + t]);
            yb[(size_t)NCELL * FD + t] = f2bf(elu_fast(a));
        }
        return;
    }

    // ---- row-pair block: grid rows r0, r0+1 (64 cells) ----
    const int r0 = rb * 2;

    // Phase 0: issue ALL global loads (main tile + halo rows + meta) before
    // the first barrier so the agg phase never waits on fresh misses.
    const ushort_t* src = xb + (size_t)(r0 * SGRID) * FD;
    uint4 mainT[4], haloT[4], metaT[4];
    const uint4 zero4 = make_uint4(0u, 0u, 0u, 0u);
    #pragma unroll
    for (int jj = 0; jj < 4; ++jj) {
        const int e8 = (t + 256 * jj) * 8;     // 0..8184
        const int cc = e8 >> 7, k = e8 & 127;
        const int rr = cc >> 5, c = cc & 31;
        mainT[jj] = *(const uint4*)(src + e8);
        const int grow = (rr == 0) ? (r0 - 1) : (r0 + 2);
        haloT[jj] = (grow >= 0 && grow < SGRID)
            ? *(const uint4*)(xb + (size_t)(grow * SGRID + c) * FD + k) : zero4;
        metaT[jj] = meta_valid
            ? *(const uint4*)(xb + (size_t)NCELL * FD + k) : zero4;
    }
    #pragma unroll
    for (int jj = 0; jj < 4; ++jj) {
        const int e8 = (t + 256 * jj) * 8;
        const int cc = e8 >> 7, k = e8 & 127;
        *(uint4*)&xt[cc * XSTR + k] = mainT[jj];
    }
    __syncthreads();

    // Build agg tile (bf16): laterals + inner vertical from LDS; halo + meta
    // from prefetched registers. Packed bf16 conversion on the way out.
    #pragma unroll
    for (int jj = 0; jj < 4; ++jj) {
        const int e8 = (t + 256 * jj) * 8;
        const int cc = e8 >> 7, k = e8 & 127;
        const int c = cc & 31;
        float s[8];
        unpack8(*(const uint4*)&xt[(cc ^ 32) * XSTR + k], s);   // inner vertical
        if (c > 0) {
            float f[8]; unpack8(*(const uint4*)&xt[(cc - 1) * XSTR + k], f);
            #pragma unroll
            for (int q = 0; q < 8; ++q) s[q] += f[q];
        }
        if (c < 31) {
            float f[8]; unpack8(*(const uint4*)&xt[(cc + 1) * XSTR + k], f);
            #pragma unroll
            for (int q = 0; q < 8; ++q) s[q] += f[q];
        }
        {
            float f[8]; unpack8(haloT[jj], f);
            #pragma unroll
            for (int q = 0; q < 8; ++q) s[q] += f[q];
        }
        {
            float f[8]; unpack8(metaT[jj], f);
            #pragma unroll
            for (int q = 0; q < 8; ++q) s[q] += f[q];
        }
        uint4 u;
        u.x = pkbf(s[0], s[1]); u.y = pkbf(s[2], s[3]);
        u.z = pkbf(s[4], s[5]); u.w = pkbf(s[6], s[7]);
        *(uint4*)&at[cc * XSTR + k] = u;
    }
    __syncthreads();

    // MFMA GEMM: M=64 (2 m-tiles) x N=128 (4 waves) x K=256.
    const int w = t >> 6;
    const int l = t & 63;
    const int m0 = l & 31;
    const int koff = (l >> 5) * 8;

    floatx16 acc0, acc1;
    #pragma unroll
    for (int q = 0; q < 16; ++q) { acc0[q] = 0.f; acc1[q] = 0.f; }

    #pragma unroll
    for (int p = 0; p < 2; ++p) {
        const ushort_t* X = p ? at : xt;
        const ushort_t* WF = wf + (size_t)((p * 4 + w) * 8) * 64 * 8;
        #pragma unroll
        for (int ks = 0; ks < 8; ++ks) {
            const short8 bfrag = *(const short8*)(WF + (size_t)(ks * 64 + l) * 8);
            const short8 av0 = *(const short8*)&X[m0 * XSTR + ks * 16 + koff];
            const short8 av1 = *(const short8*)&X[(m0 + 32) * XSTR + ks * 16 + koff];
            acc0 = __builtin_amdgcn_mfma_f32_32x32x16_bf16(av0, bfrag, acc0, 0, 0, 0);
            acc1 = __builtin_amdgcn_mfma_f32_32x32x16_bf16(av1, bfrag, acc1, 0, 0, 0);
        }
    }
    __syncthreads();   // all waves done reading xt -> safe to reuse as out tile

    // Epilogue: bias + fast elu -> LDS (bf16) -> coalesced uint4 stores.
    // C/D map: col=lane&31, row=(reg&3)+8*(reg>>2)+4*(lane>>5).
    const int col = w * 32 + (l & 31);
    const float bias = bf2f(bsl[col]);
    #pragma unroll
    for (int mt = 0; mt < 2; ++mt) {
        const floatx16 A = mt ? acc1 : acc0;
        #pragma unroll
        for (int r = 0; r < 16; ++r) {
            const int rowC = (r & 3) + 8 * (r >> 2) + 4 * (l >> 5);
            xt[(mt * 32 + rowC) * XSTR + col] = f2bf(elu_fast(A[r] + bias));
        }
    }
    __syncthreads();
    ushort_t* dst = yb + (size_t)(r0 * SGRID) * FD;
    #pragma unroll
    for (int jj = 0; jj < 4; ++jj) {
        const int e8 = (t + 256 * jj) * 8;
        const int cc = e8 >> 7, k = e8 & 127;
        *(uint4*)(dst + e8) = *(const uint4*)&xt[cc * XSTR + k];
    }
}

// ---------------------------------------------------------------------------
// Fused GNN: frag-setup + 3 layers in one cooperative kernel.
// 1024 blocks x 256 threads = exactly 4 blocks/CU co-resident
// (34.8 KB LDS <= 40 KB, launch_bounds(256,4) caps VGPR at 128).
// Grid-stride over 2176 tasks/layer; grid.sync() between layers.
// ---------------------------------------------------------------------------
__global__ __launch_bounds__(256, 4) void fused_gnn(
    const ushort_t* __restrict__ gmap,
    ushort_t* __restrict__ x1,
    ushort_t* __restrict__ x2,
    ushort_t* __restrict__ wfrag,
    const ushort_t* __restrict__ Ws,
    const ushort_t* __restrict__ Wn,
    const ushort_t* __restrict__ bs)
{
    cg::grid_group grid = cg::this_grid();
    const int t = threadIdx.x;

    __shared__ alignas(16) ushort_t xt[64 * XSTR];   // 17.4 KB
    __shared__ alignas(16) ushort_t at[64 * XSTR];   // 17.4 KB

    // ---- Phase A: pack MFMA B-fragments (12288 groups on blocks 0..47) ----
    {
        const int g = blockIdx.x * 256 + t;
        if (g < 3 * 2 * 4 * 8 * 64) {
            const int lane = g & 63;
            const int ks   = (g >> 6) & 7;
            const int nt   = (g >> 9) & 3;
            const int p    = (g >> 11) & 1;
            const int l    = g >> 12;
            const ushort_t* W = (p ? Wn : Ws) + (size_t)l * FD * FD;
            const int k0  = ks * 16 + (lane >> 5) * 8;
            const int col = nt * 32 + (lane & 31);
            ushort_t v[8];
            #pragma unroll
            for (int jj = 0; jj < 8; ++jj) v[jj] = W[(size_t)(k0 + jj) * FD + col];
            uint4 u;
            u.x = v[0] | ((uint_t)v[1] << 16); u.y = v[2] | ((uint_t)v[3] << 16);
            u.z = v[4] | ((uint_t)v[5] << 16); u.w = v[6] | ((uint_t)v[7] << 16);
            *(uint4*)(wfrag + (size_t)g * 8) = u;
        }
    }
    grid.sync();

    // ---- 3 GNN layers ----
    #pragma unroll 1
    for (int l = 0; l < 3; ++l) {
        const ushort_t* xin  = (l == 0) ? gmap : ((l == 1) ? x1 : x2);
        ushort_t*       xout = (l == 1) ? x2 : x1;
        const int mv      = (l == 0) ? 0 : 1;
        const int bstride = (l == 0) ? (NCELL * FD) : (NTOT * FD);
        const ushort_t* wf  = wfrag + l * 32768;
        const ushort_t* Wsl = Ws + (size_t)l * FD * FD;
        const ushort_t* Wnl = Wn + (size_t)l * FD * FD;
        const ushort_t* bsl = bs + l * FD;
        #pragma unroll 1
        for (int tau = blockIdx.x; tau < 17 * BATCH; tau += gridDim.x) {
            gnn_task(tau, t, xin, xout, wf, Wsl, Wnl, bsl, mv, bstride, xt, at);
            __syncthreads();   // LDS reuse fence between tasks
        }
        if (l < 2) grid.sync();
    }
}

// ---------------------------------------------------------------------------
// Head: gather + 6-layer MLP + mask. 128 blocks (XCD-swizzled, 1 batch each)
// x 1024 threads = 16 waves doing a 16-way K-split; partials reduced via
// part[16][512] in LDS. LDS ~39 KB.
// ---------------------------------------------------------------------------
__global__ __launch_bounds__(1024) void head_kernel(
    const ushort_t* __restrict__ x,       // bf16, B x 1025 x 128
    const int* __restrict__ pos,
    const int* __restrict__ amask,
    const ushort_t* __restrict__ Wd1, const ushort_t* __restrict__ bd1,
    const ushort_t* __restrict__ Wd2, const ushort_t* __restrict__ bd2,
    const ushort_t* __restrict__ Wd3, const ushort_t* __restrict__ bd3,
    const ushort_t* __restrict__ Wp1, const ushort_t* __restrict__ bp1,
    const ushort_t* __restrict__ Wp2, const ushort_t* __restrict__ bp2,
    const ushort_t* __restrict__ Wp3, const ushort_t* __restrict__ bp3,
    ushort_t* __restrict__ out)           // bf16, B x 19
{
    const int t = threadIdx.x;
    const int b = (blockIdx.x & 7) * 16 + (blockIdx.x >> 3);  // batch on its XCD
    const int q = t >> 6;             // K-split sixteenth (wave id, 0..15)
    const int lane = t & 63;

    __shared__ float st[640];
    __shared__ float bufA[512];
    __shared__ float bufB[512];
    __shared__ float part[16][512];

    const int OFFR[5] = {-1, 0, 1, 0, 0};
    const int OFFC[5] = {0, -1, 0, 1, 0};

    // Gather state (reference's j=(pos+off+1)@[32,1] into 34-wide padded map).
    {
        const int pr = pos[b * 2 + 0], pc = pos[b * 2 + 1];
        for (int e = t; e < 640; e += 1024) {
            const int slot = e >> 7, k = e & 127;
            const int jj = (pr + OFFR[slot] + 1) * SGRID + (pc + OFFC[slot] + 1);
            const int qr = jj / (SGRID + 2), qc = jj % (SGRID + 2);
            float v = 0.f;
            if (qr >= 1 && qr <= SGRID && qc >= 1 && qc <= SGRID)
                v = bf2f(x[((size_t)b * NTOT + (qr - 1) * SGRID + (qc - 1)) * FD + k]);
            st[e] = v;
        }
    }
    __syncthreads();

    // ---- L1: 640 -> 512 (K/16 = 40 per wave; lane owns 8 cols) ----
    {
        float acc[8];
        #pragma unroll
        for (int p = 0; p < 8; ++p) acc[p] = 0.f;
        const int c0 = lane * 8;
        const int kb = q * 40;
        #pragma unroll 8
        for (int k = kb; k < kb + 40; ++k) {
            const float s = st[k];
            float f[8]; unpack8(*(const uint4*)(Wd1 + (size_t)k * 512 + c0), f);
            #pragma unroll
            for (int p = 0; p < 8; ++p) acc[p] += s * f[p];
        }
        #pragma unroll
        for (int p = 0; p < 8; ++p) part[q][c0 + p] = acc[p];
        __syncthreads();
        if (t < 512) {
            float a = bf2f(bd1[t]);
            #pragma unroll
            for (int p = 0; p < 16; ++p) a += part[p][t];
            bufA[t] = elu_fast(a);
        }
        __syncthreads();
    }
    // ---- L2: 512 -> 512 (K/16 = 32) ----
    {
        float acc[8];
        #pragma unroll
        for (int p = 0; p < 8; ++p) acc[p] = 0.f;
        const int c0 = lane * 8;
        const int kb = q * 32;
        #pragma unroll 8
        for (int k = kb; k < kb + 32; ++k) {
            const float s = bufA[k];
            float f[8]; unpack8(*(const uint4*)(Wd2 + (size_t)k * 512 + c0), f);
            #pragma unroll
            for (int p = 0; p < 8; ++p) acc[p] += s * f[p];
        }
        #pragma unroll
        for (int p = 0; p < 8; ++p) part[q][c0 + p] = acc[p];
        __syncthreads();
        if (t < 512) {
            float a = bf2f(bd2[t]);
            #pragma unroll
            for (int p = 0; p < 16; ++p) a += part[p][t];
            bufB[t] = elu_fast(a);
        }
        __syncthreads();
    }
    // ---- L3: 512 -> 256 (K/16 = 32; out -> st[0..255]) ----
    {
        float acc[4];
        #pragma unroll
        for (int p = 0; p < 4; ++p) acc[p] = 0.f;
        const int c0 = lane * 4;
        const int kb = q * 32;
        #pragma unroll 8
        for (int k = kb; k < kb + 32; ++k) {
            const float s = bufB[k];
            float f[4]; unpack4(*(const uint2*)(Wd3 + (size_t)k * 256 + c0), f);
            #pragma unroll
            for (int p = 0; p < 4; ++p) acc[p] += s * f[p];
        }
        #pragma unroll
        for (int p = 0; p < 4; ++p) part[q][c0 + p] = acc[p];
        __syncthreads();
        if (t < 256) {
            float a = bf2f(bd3[t]);
            #pragma unroll
            for (int p = 0; p < 16; ++p) a += part[p][t];
            st[t] = elu_fast(a);
        }
        __syncthreads();
    }
    // ---- L4: 256 -> 256 (K/16 = 16; st -> bufA) ----
    {
        float acc[4];
        #pragma unroll
        for (int p = 0; p < 4; ++p) acc[p] = 0.f;
        const int c0 = lane * 4;
        const int kb = q * 16;
        #pragma unroll 8
        for (int k = kb; k < kb + 16; ++k) {
            const float s = st[k];
            float f[4]; unpack4(*(const uint2*)(Wp1 + (size_t)k * 256 + c0), f);
            #pragma unroll
            for (int p = 0; p < 4; ++p) acc[p] += s * f[p];
        }
        #pragma unroll
        for (int p = 0; p < 4; ++p) part[q][c0 + p] = acc[p];
        __syncthreads();
        if (t < 256) {
            float a = bf2f(bp1[t]);
            #pragma unroll
            for (int p = 0; p < 16; ++p) a += part[p][t];
            bufA[t] = elu_fast(a);
        }
        __syncthreads();
    }
    // ---- L5: 256 -> 256 (bufA -> bufB) ----
    {
        float acc[4];
        #pragma unroll
        for (int p = 0; p < 4; ++p) acc[p] = 0.f;
        const int c0 = lane * 4;
        const int kb = q * 16;
        #pragma unroll 8
        for (int k = kb; k < kb + 16; ++k) {
            const float s = bufA[k];
            float f[4]; unpack4(*(const uint2*)(Wp2 + (size_t)k * 256 + c0), f);
            #pragma unroll
            for (int p = 0; p < 4; ++p) acc[p] += s * f[p];
        }
        #pragma unroll
        for (int p = 0; p < 4; ++p) part[q][c0 + p] = acc[p];
        __syncthreads();
        if (t < 256) {
            float a = bf2f(bp2[t]);
            #pragma unroll
            for (int p = 0; p < 16; ++p) a += part[p][t];
            bufB[t] = elu_fast(a);
        }
        __syncthreads();
    }
    // ---- L6: 256 -> 19 + mask, finite-clamped bf16 ----
    {
        float a = 0.f;
        const int kb = q * 16;
        if (lane < NACT) {
            #pragma unroll 8
            for (int k = kb; k < kb + 16; ++k)
                a += bufB[k] * bf2f(Wp3[(size_t)k * NACT + lane]);
            part[q][lane] = a;
        }
        __syncthreads();
        if (t < NACT) {
            float v = bf2f(bp3[t]);
            #pragma unroll
            for (int p = 0; p < 16; ++p) v += part[p][t];
            v += amask[b * NACT + t] ? 0.f : NEG_INF_F;
            v = fminf(fmaxf(v, -BF16_SAFE_F), BF16_SAFE_F);
            out[b * NACT + t] = f2bf(v);
        }
    }
}

extern "C" void kernel_launch(void* const* d_in, const int* in_sizes, int n_in,
                              void* d_out, int out_size, void* d_ws, size_t ws_size,
                              hipStream_t stream) {
    const ushort_t* gmap  = (const ushort_t*)d_in[0];
    const int*      pos   = (const int*)     d_in[1];
    const int*      amask = (const int*)     d_in[2];
    const ushort_t* Ws    = (const ushort_t*)d_in[3];
    const ushort_t* Wn    = (const ushort_t*)d_in[4];
    const ushort_t* bs    = (const ushort_t*)d_in[5];
    const ushort_t* Wd1   = (const ushort_t*)d_in[6];
    const ushort_t* bd1   = (const ushort_t*)d_in[7];
    const ushort_t* Wd2   = (const ushort_t*)d_in[8];
    const ushort_t* bd2   = (const ushort_t*)d_in[9];
    const ushort_t* Wd3   = (const ushort_t*)d_in[10];
    const ushort_t* bd3   = (const ushort_t*)d_in[11];
    const ushort_t* Wp1   = (const ushort_t*)d_in[12];
    const ushort_t* bp1   = (const ushort_t*)d_in[13];
    const ushort_t* Wp2   = (const ushort_t*)d_in[14];
    const ushort_t* bp2   = (const ushort_t*)d_in[15];
    const ushort_t* Wp3   = (const ushort_t*)d_in[16];
    const ushort_t* bp3   = (const ushort_t*)d_in[17];

    // Workspace: 2 bf16 activation buffers (33.6 MB ea) + 192 KB weight frags.
    ushort_t* x1 = (ushort_t*)d_ws;
    ushort_t* x2 = x1 + (size_t)BATCH * NTOT * FD;
    ushort_t* wfrag = x2 + (size_t)BATCH * NTOT * FD;

    void* args[] = {
        (void*)&gmap, (void*)&x1, (void*)&x2, (void*)&wfrag,
        (void*)&Ws, (void*)&Wn, (void*)&bs
    };
    // 1024 blocks x 256 threads: exactly 4 blocks/CU co-resident
    // (LDS 34.8 KB, VGPR cap 128) -> cooperative launch valid.
    hipLaunchCooperativeKernel((const void*)fused_gnn,
                               dim3(1024), dim3(256), args, 0, stream);

    head_kernel<<<BATCH, 1024, 0, stream>>>(x1, pos, amask,
                                            Wd1, bd1, Wd2, bd2, Wd3, bd3,
                                            Wp1, bp1, Wp2, bp2, Wp3, bp3,
                                            (ushort_t*)d_out);
}

// Round 4
// 242.142 us; speedup vs baseline: 2.7129x; 2.7129x over previous
//
#include <hip/hip_runtime.h>
#include <hip/hip_bf16.h>

#define BATCH 128
#define SGRID 32
#define NCELL 1024
#define NTOT  1025
#define FD    128
#define NACT  19
#define NEG_INF_F  (-3.4028234663852886e38f)  // jnp.finfo(float32).min
#define BF16_SAFE_F (3.3e38f)                 // < bf16 max finite (3.3895e38)
#define XSTR 136                              // LDS row stride (bf16); 272B keeps b128 align

typedef unsigned short ushort_t;
typedef unsigned int   uint_t;
typedef short   short8   __attribute__((ext_vector_type(8)));
typedef float   floatx16 __attribute__((ext_vector_type(16)));

__device__ __forceinline__ float elu_fast(float v) {   // bf16-accurate ELU
    return v > 0.f ? v : (__expf(v) - 1.f);
}
__device__ __forceinline__ float bf2f(ushort_t h) {
    union { uint_t u; float f; } v; v.u = ((uint_t)h) << 16; return v.f;
}
__device__ __forceinline__ ushort_t f2bf(float f) {   // round-to-nearest-even
    union { float f; uint_t u; } v; v.f = f;
    uint_t r = v.u + 0x7FFFu + ((v.u >> 16) & 1u);
    return (ushort_t)(r >> 16);
}
__device__ __forceinline__ uint_t pkbf(float a, float b) {  // v_cvt_pk_bf16_f32
    union { __hip_bfloat162 h; uint_t u; } v;
    v.h = __float22bfloat162_rn(make_float2(a, b));
    return v.u;
}
__device__ __forceinline__ void unpack2(uint_t u, float& a, float& b) {
    union { uint_t x; float f; } lo, hi;
    lo.x = u << 16; hi.x = u & 0xFFFF0000u;
    a = lo.f; b = hi.f;
}
__device__ __forceinline__ void unpack8(uint4 v, float* f) {
    unpack2(v.x, f[0], f[1]); unpack2(v.y, f[2], f[3]);
    unpack2(v.z, f[4], f[5]); unpack2(v.w, f[6], f[7]);
}
__device__ __forceinline__ void unpack4(uint2 v, float* f) {
    unpack2(v.x, f[0], f[1]); unpack2(v.y, f[2], f[3]);
}

// ---------------------------------------------------------------------------
// Pack GNN weights into MFMA B-fragment order for v_mfma_f32_32x32x16_bf16:
// B[k][n], lane layout n = lane&31, k = (lane>>5)*8 + j (j=0..7).
// group g = ((layer*2 + phase)*4 + ntile)*8*64 + ks*64 + lane; 8 bf16/group.
// ---------------------------------------------------------------------------
__global__ __launch_bounds__(256) void gnn_setup_frags(
    const ushort_t* __restrict__ Ws,   // 3 x 128 x 128, k-major
    const ushort_t* __restrict__ Wn,
    ushort_t* __restrict__ wfrag)
{
    const int g = blockIdx.x * 256 + threadIdx.x;   // 12288 groups
    if (g >= 3 * 2 * 4 * 8 * 64) return;
    const int lane = g & 63;
    const int ks   = (g >> 6) & 7;
    const int nt   = (g >> 9) & 3;
    const int p    = (g >> 11) & 1;
    const int l    = g >> 12;
    const ushort_t* W = (p ? Wn : Ws) + (size_t)l * FD * FD;
    const int k0  = ks * 16 + (lane >> 5) * 8;
    const int col = nt * 32 + (lane & 31);
    ushort_t v[8];
    #pragma unroll
    for (int j = 0; j < 8; ++j) v[j] = W[(size_t)(k0 + j) * FD + col];
    uint4 u;
    u.x = v[0] | ((uint_t)v[1] << 16); u.y = v[2] | ((uint_t)v[3] << 16);
    u.z = v[4] | ((uint_t)v[5] << 16); u.w = v[6] | ((uint_t)v[7] << 16);
    *(uint4*)(wfrag + (size_t)g * 8) = u;
}

// ---------------------------------------------------------------------------
// GNN layer — byte-identical to the proven 235-µs R0 version.
// ---------------------------------------------------------------------------
__global__ __launch_bounds__(256, 4) void gnn_layer(
    const ushort_t* __restrict__ xprev,
    ushort_t* __restrict__ xnext,
    const ushort_t* __restrict__ wfrag_layer,
    const ushort_t* __restrict__ Ws,           // raw weights (meta block only)
    const ushort_t* __restrict__ Wn,
    const ushort_t* __restrict__ bs,
    int meta_valid, int in_bstride)
{
    const int i = blockIdx.x;
    const int xcd = i & 7;
    const int j = i >> 3;
    const int b = xcd * 16 + j / 17;
    const int rb = j % 17;
    const int t = threadIdx.x;
    const ushort_t* xb = xprev + (size_t)b * in_bstride;
    ushort_t* yb = xnext + (size_t)b * (NTOT * FD);

    __shared__ alignas(16) ushort_t xt[64 * XSTR];   // x tile / meta scratch
    __shared__ alignas(16) ushort_t at[64 * XSTR];   // agg tile / meta scratch

    if (rb == 16) {
        // ---- meta node: reduce 1024 cells, then 1x128 GEMM ----
        float* part = (float*)xt;
        float* msum = (float*)at;
        float* xm   = (float*)at + FD;
        const int kc = (t & 15) * 8;
        const int cg = t >> 4;
        float s[8];
        #pragma unroll
        for (int q = 0; q < 8; ++q) s[q] = 0.f;
        #pragma unroll 4
        for (int n = 0; n < 64; ++n) {
            const int cell = cg * 64 + n;
            float f[8]; unpack8(*(const uint4*)(xb + (size_t)cell * FD + kc), f);
            #pragma unroll
            for (int q = 0; q < 8; ++q) s[q] += f[q];
        }
        #pragma unroll
        for (int q = 0; q < 8; ++q) part[cg * FD + kc + q] = s[q];
        __syncthreads();
        if (t < FD) {
            float a = 0.f;
            #pragma unroll
            for (int gI = 0; gI < 16; ++gI) a += part[gI * FD + t];
            msum[t] = a;
            xm[t] = meta_valid ? bf2f(xb[(size_t)NCELL * FD + t]) : 0.f;
        }
        __syncthreads();
        if (t < FD) {
            float a = bf2f(bs[t]);
            #pragma unroll 4
            for (int kk = 0; kk < FD; ++kk)
                a += xm[kk] * bf2f(Ws[kk * FD + t]) + msum[kk] * bf2f(Wn[kk * FD + t]);
            yb[(size_t)NCELL * FD + t] = f2bf(elu_fast(a));
        }
        return;
    }

    // ---- row-pair block: grid rows r0, r0+1 (64 cells) ----
    const int r0 = rb * 2;

    const ushort_t* src = xb + (size_t)(r0 * SGRID) * FD;
    uint4 mainT[4], haloT[4], metaT[4];
    const uint4 zero4 = make_uint4(0u, 0u, 0u, 0u);
    #pragma unroll
    for (int jj = 0; jj < 4; ++jj) {
        const int e8 = (t + 256 * jj) * 8;     // 0..8184
        const int cc = e8 >> 7, k = e8 & 127;
        const int rr = cc >> 5, c = cc & 31;
        mainT[jj] = *(const uint4*)(src + e8);
        const int grow = (rr == 0) ? (r0 - 1) : (r0 + 2);
        haloT[jj] = (grow >= 0 && grow < SGRID)
            ? *(const uint4*)(xb + (size_t)(grow * SGRID + c) * FD + k) : zero4;
        metaT[jj] = meta_valid
            ? *(const uint4*)(xb + (size_t)NCELL * FD + k) : zero4;
    }
    #pragma unroll
    for (int jj = 0; jj < 4; ++jj) {
        const int e8 = (t + 256 * jj) * 8;
        const int cc = e8 >> 7, k = e8 & 127;
        *(uint4*)&xt[cc * XSTR + k] = mainT[jj];
    }
    __syncthreads();

    // Build agg tile (bf16): laterals + inner vertical from LDS; halo + meta
    // from prefetched registers. Packed bf16 conversion on the way out.
    #pragma unroll
    for (int jj = 0; jj < 4; ++jj) {
        const int e8 = (t + 256 * jj) * 8;
        const int cc = e8 >> 7, k = e8 & 127;
        const int c = cc & 31;
        float s[8];
        unpack8(*(const uint4*)&xt[(cc ^ 32) * XSTR + k], s);   // inner vertical
        if (c > 0) {
            float f[8]; unpack8(*(const uint4*)&xt[(cc - 1) * XSTR + k], f);
            #pragma unroll
            for (int q = 0; q < 8; ++q) s[q] += f[q];
        }
        if (c < 31) {
            float f[8]; unpack8(*(const uint4*)&xt[(cc + 1) * XSTR + k], f);
            #pragma unroll
            for (int q = 0; q < 8; ++q) s[q] += f[q];
        }
        {
            float f[8]; unpack8(haloT[jj], f);
            #pragma unroll
            for (int q = 0; q < 8; ++q) s[q] += f[q];
        }
        {
            float f[8]; unpack8(metaT[jj], f);
            #pragma unroll
            for (int q = 0; q < 8; ++q) s[q] += f[q];
        }
        uint4 u;
        u.x = pkbf(s[0], s[1]); u.y = pkbf(s[2], s[3]);
        u.z = pkbf(s[4], s[5]); u.w = pkbf(s[6], s[7]);
        *(uint4*)&at[cc * XSTR + k] = u;
    }
    __syncthreads();

    // MFMA GEMM: M=64 (2 m-tiles) x N=128 (4 waves) x K=256.
    const int w = t >> 6;
    const int l = t & 63;
    const int m0 = l & 31;
    const int koff = (l >> 5) * 8;

    floatx16 acc0, acc1;
    #pragma unroll
    for (int q = 0; q < 16; ++q) { acc0[q] = 0.f; acc1[q] = 0.f; }

    #pragma unroll
    for (int p = 0; p < 2; ++p) {
        const ushort_t* X = p ? at : xt;
        const ushort_t* WF = wfrag_layer + (size_t)((p * 4 + w) * 8) * 64 * 8;
        #pragma unroll
        for (int ks = 0; ks < 8; ++ks) {
            const short8 bfrag = *(const short8*)(WF + (size_t)(ks * 64 + l) * 8);
            const short8 av0 = *(const short8*)&X[m0 * XSTR + ks * 16 + koff];
            const short8 av1 = *(const short8*)&X[(m0 + 32) * XSTR + ks * 16 + koff];
            acc0 = __builtin_amdgcn_mfma_f32_32x32x16_bf16(av0, bfrag, acc0, 0, 0, 0);
            acc1 = __builtin_amdgcn_mfma_f32_32x32x16_bf16(av1, bfrag, acc1, 0, 0, 0);
        }
    }
    __syncthreads();   // all waves done reading xt -> safe to reuse as out tile

    // Epilogue: bias + fast elu -> LDS (bf16) -> coalesced uint4 stores.
    const int col = w * 32 + (l & 31);
    const float bias = bf2f(bs[col]);
    #pragma unroll
    for (int mt = 0; mt < 2; ++mt) {
        const floatx16 A = mt ? acc1 : acc0;
        #pragma unroll
        for (int r = 0; r < 16; ++r) {
            const int rowC = (r & 3) + 8 * (r >> 2) + 4 * (l >> 5);
            xt[(mt * 32 + rowC) * XSTR + col] = f2bf(elu_fast(A[r] + bias));
        }
    }
    __syncthreads();
    ushort_t* dst = yb + (size_t)(r0 * SGRID) * FD;
    #pragma unroll
    for (int jj = 0; jj < 4; ++jj) {
        const int e8 = (t + 256 * jj) * 8;
        const int cc = e8 >> 7, k = e8 & 127;
        *(uint4*)(dst + e8) = *(const uint4*)&xt[cc * XSTR + k];
    }
}

// ---------------------------------------------------------------------------
// Head L1 (640 -> 512), split across ALL CUs: 1024 blocks x 256 threads.
// Block (b, cb): batch b, cols [cb*64, cb*64+64). 4 waves = 4-way K-split
// (160 k each); lane owns 1 col. Redundant per-block gather (cheap, L2-hot).
// Writes h1[b][512] f32 (post-ELU) to workspace.
// ---------------------------------------------------------------------------
__global__ __launch_bounds__(256) void head_l1(
    const ushort_t* __restrict__ x,       // bf16, B x 1025 x 128 (layer-3 out)
    const int* __restrict__ pos,
    const ushort_t* __restrict__ Wd1, const ushort_t* __restrict__ bd1,
    float* __restrict__ h1)               // f32, B x 512
{
    const int i = blockIdx.x;
    const int xcd = i & 7;
    const int j = i >> 3;                  // 0..127
    const int b  = xcd * 16 + (j >> 3);    // batch on its XCD
    const int cb = j & 7;                  // col block (64 cols)
    const int t = threadIdx.x;
    const int q = t >> 6;                  // wave 0..3
    const int lane = t & 63;

    __shared__ float st[640];
    __shared__ float part[4][64];

    const int OFFR[5] = {-1, 0, 1, 0, 0};
    const int OFFC[5] = {0, -1, 0, 1, 0};

    // Gather state (reference's j=(pos+off+1)@[32,1] into 34-wide padded map).
    {
        const int pr = pos[b * 2 + 0], pc = pos[b * 2 + 1];
        for (int e = t; e < 640; e += 256) {
            const int slot = e >> 7, k = e & 127;
            const int jj = (pr + OFFR[slot] + 1) * SGRID + (pc + OFFC[slot] + 1);
            const int qr = jj / (SGRID + 2), qc = jj % (SGRID + 2);
            float v = 0.f;
            if (qr >= 1 && qr <= SGRID && qc >= 1 && qc <= SGRID)
                v = bf2f(x[((size_t)b * NTOT + (qr - 1) * SGRID + (qc - 1)) * FD + k]);
            st[e] = v;
        }
    }
    __syncthreads();

    const int c = cb * 64 + lane;          // this lane's output column
    float acc = 0.f;
    const int kb = q * 160;
    #pragma unroll 8
    for (int k = kb; k < kb + 160; ++k)
        acc += st[k] * bf2f(Wd1[(size_t)k * 512 + c]);
    part[q][lane] = acc;
    __syncthreads();
    if (t < 64) {
        float a = bf2f(bd1[c - (c & 63) + t]);   // = bd1[cb*64 + t]
        #pragma unroll
        for (int p = 0; p < 4; ++p) a += part[p][t];
        h1[(size_t)b * 512 + cb * 64 + t] = elu_fast(a);
    }
}

// ---------------------------------------------------------------------------
// Head L2-L6: 128 blocks (XCD-swizzled, 1 batch) x 512 threads = 8 waves,
// 8-way K-split, partials via part[8][512] in LDS (~20 KB total).
// ---------------------------------------------------------------------------
__global__ __launch_bounds__(512) void head_kernel(
    const float* __restrict__ h1,         // f32, B x 512 (post-ELU L1)
    const int* __restrict__ amask,
    const ushort_t* __restrict__ Wd2, const ushort_t* __restrict__ bd2,
    const ushort_t* __restrict__ Wd3, const ushort_t* __restrict__ bd3,
    const ushort_t* __restrict__ Wp1, const ushort_t* __restrict__ bp1,
    const ushort_t* __restrict__ Wp2, const ushort_t* __restrict__ bp2,
    const ushort_t* __restrict__ Wp3, const ushort_t* __restrict__ bp3,
    ushort_t* __restrict__ out)           // bf16, B x 19
{
    const int t = threadIdx.x;
    const int b = (blockIdx.x & 7) * 16 + (blockIdx.x >> 3);  // batch on its XCD
    const int q = t >> 6;             // wave id 0..7
    const int lane = t & 63;

    __shared__ float bufA[512];
    __shared__ float bufB[512];
    __shared__ float part[8][512];

    // Load L1 activations.
    bufA[t] = h1[(size_t)b * 512 + t];
    __syncthreads();

    // ---- L2: 512 -> 512 (64 k per wave; lane owns 8 cols) ----
    {
        float acc[8];
        #pragma unroll
        for (int p = 0; p < 8; ++p) acc[p] = 0.f;
        const int c0 = lane * 8;
        const int kb = q * 64;
        #pragma unroll 8
        for (int k = kb; k < kb + 64; ++k) {
            const float s = bufA[k];
            float f[8]; unpack8(*(const uint4*)(Wd2 + (size_t)k * 512 + c0), f);
            #pragma unroll
            for (int p = 0; p < 8; ++p) acc[p] += s * f[p];
        }
        #pragma unroll
        for (int p = 0; p < 8; ++p) part[q][c0 + p] = acc[p];
        __syncthreads();
        {
            float a = bf2f(bd2[t]);
            #pragma unroll
            for (int p = 0; p < 8; ++p) a += part[p][t];
            bufB[t] = elu_fast(a);
        }
        __syncthreads();
    }
    // ---- L3: 512 -> 256 (64 k per wave; lane owns 4 cols; out -> bufA) ----
    {
        float acc[4];
        #pragma unroll
        for (int p = 0; p < 4; ++p) acc[p] = 0.f;
        const int c0 = lane * 4;
        const int kb = q * 64;
        #pragma unroll 8
        for (int k = kb; k < kb + 64; ++k) {
            const float s = bufB[k];
            float f[4]; unpack4(*(const uint2*)(Wd3 + (size_t)k * 256 + c0), f);
            #pragma unroll
            for (int p = 0; p < 4; ++p) acc[p] += s * f[p];
        }
        #pragma unroll
        for (int p = 0; p < 4; ++p) part[q][c0 + p] = acc[p];
        __syncthreads();
        if (t < 256) {
            float a = bf2f(bd3[t]);
            #pragma unroll
            for (int p = 0; p < 8; ++p) a += part[p][t];
            bufA[t] = elu_fast(a);
        }
        __syncthreads();
    }
    // ---- L4: 256 -> 256 (32 k per wave; bufA -> bufB) ----
    {
        float acc[4];
        #pragma unroll
        for (int p = 0; p < 4; ++p) acc[p] = 0.f;
        const int c0 = lane * 4;
        const int kb = q * 32;
        #pragma unroll 8
        for (int k = kb; k < kb + 32; ++k) {
            const float s = bufA[k];
            float f[4]; unpack4(*(const uint2*)(Wp1 + (size_t)k * 256 + c0), f);
            #pragma unroll
            for (int p = 0; p < 4; ++p) acc[p] += s * f[p];
        }
        #pragma unroll
        for (int p = 0; p < 4; ++p) part[q][c0 + p] = acc[p];
        __syncthreads();
        if (t < 256) {
            float a = bf2f(bp1[t]);
            #pragma unroll
            for (int p = 0; p < 8; ++p) a += part[p][t];
            bufB[t] = elu_fast(a);
        }
        __syncthreads();
    }
    // ---- L5: 256 -> 256 (bufB -> bufA) ----
    {
        float acc[4];
        #pragma unroll
        for (int p = 0; p < 4; ++p) acc[p] = 0.f;
        const int c0 = lane * 4;
        const int kb = q * 32;
        #pragma unroll 8
        for (int k = kb; k < kb + 32; ++k) {
            const float s = bufB[k];
            float f[4]; unpack4(*(const uint2*)(Wp2 + (size_t)k * 256 + c0), f);
            #pragma unroll
            for (int p = 0; p < 4; ++p) acc[p] += s * f[p];
        }
        #pragma unroll
        for (int p = 0; p < 4; ++p) part[q][c0 + p] = acc[p];
        __syncthreads();
        if (t < 256) {
            float a = bf2f(bp2[t]);
            #pragma unroll
            for (int p = 0; p < 8; ++p) a += part[p][t];
            bufA[t] = elu_fast(a);
        }
        __syncthreads();
    }
    // ---- L6: 256 -> 19 + mask, finite-clamped bf16 ----
    {
        float a = 0.f;
        const int kb = q * 32;
        if (lane < NACT) {
            #pragma unroll 8
            for (int k = kb; k < kb + 32; ++k)
                a += bufA[k] * bf2f(Wp3[(size_t)k * NACT + lane]);
            part[q][lane] = a;
        }
        __syncthreads();
        if (t < NACT) {
            float v = bf2f(bp3[t]);
            #pragma unroll
            for (int p = 0; p < 8; ++p) v += part[p][t];
            v += amask[b * NACT + t] ? 0.f : NEG_INF_F;
            v = fminf(fmaxf(v, -BF16_SAFE_F), BF16_SAFE_F);
            out[b * NACT + t] = f2bf(v);
        }
    }
}

extern "C" void kernel_launch(void* const* d_in, const int* in_sizes, int n_in,
                              void* d_out, int out_size, void* d_ws, size_t ws_size,
                              hipStream_t stream) {
    const ushort_t* gmap  = (const ushort_t*)d_in[0];
    const int*      pos   = (const int*)     d_in[1];
    const int*      amask = (const int*)     d_in[2];
    const ushort_t* Ws    = (const ushort_t*)d_in[3];
    const ushort_t* Wn    = (const ushort_t*)d_in[4];
    const ushort_t* bs    = (const ushort_t*)d_in[5];
    const ushort_t* Wd1   = (const ushort_t*)d_in[6];
    const ushort_t* bd1   = (const ushort_t*)d_in[7];
    const ushort_t* Wd2   = (const ushort_t*)d_in[8];
    const ushort_t* bd2   = (const ushort_t*)d_in[9];
    const ushort_t* Wd3   = (const ushort_t*)d_in[10];
    const ushort_t* bd3   = (const ushort_t*)d_in[11];
    const ushort_t* Wp1   = (const ushort_t*)d_in[12];
    const ushort_t* bp1   = (const ushort_t*)d_in[13];
    const ushort_t* Wp2   = (const ushort_t*)d_in[14];
    const ushort_t* bp2   = (const ushort_t*)d_in[15];
    const ushort_t* Wp3   = (const ushort_t*)d_in[16];
    const ushort_t* bp3   = (const ushort_t*)d_in[17];

    // Workspace: 2 bf16 activation buffers (33.6 MB ea) + 192 KB weight frags
    // + 256 KB f32 h1 buffer.
    ushort_t* x1 = (ushort_t*)d_ws;
    ushort_t* x2 = x1 + (size_t)BATCH * NTOT * FD;
    ushort_t* wfrag = x2 + (size_t)BATCH * NTOT * FD;
    float*    h1 = (float*)(wfrag + 3 * 2 * 4 * 8 * 64 * 8);

    gnn_setup_frags<<<48, 256, 0, stream>>>(Ws, Wn, wfrag);

    const int nblk = 17 * BATCH;   // 2176, XCD-swizzled inside the kernel
    gnn_layer<<<nblk, 256, 0, stream>>>(gmap, x1, wfrag,
                                        Ws, Wn, bs, 0, NCELL * FD);
    gnn_layer<<<nblk, 256, 0, stream>>>(x1, x2, wfrag + 32768,
                                        Ws + FD * FD, Wn + FD * FD, bs + FD, 1, NTOT * FD);
    gnn_layer<<<nblk, 256, 0, stream>>>(x2, x1, wfrag + 65536,
                                        Ws + 2 * FD * FD, Wn + 2 * FD * FD, bs + 2 * FD, 1, NTOT * FD);

    head_l1<<<1024, 256, 0, stream>>>(x1, pos, Wd1, bd1, h1);

    head_kernel<<<BATCH, 512, 0, stream>>>(h1, amask,
                                           Wd2, bd2, Wd3, bd3,
                                           Wp1, bp1, Wp2, bp2, Wp3, bp3,
                                           (ushort_t*)d_out);
}

// Round 5
// 226.153 us; speedup vs baseline: 2.9047x; 1.0707x over previous
//
#include <hip/hip_runtime.h>
#include <hip/hip_bf16.h>

#define BATCH 128
#define SGRID 32
#define NCELL 1024
#define NTOT  1025
#define FD    128
#define NACT  19
#define NEG_INF_F  (-3.4028234663852886e38f)  // jnp.finfo(float32).min
#define BF16_SAFE_F (3.3e38f)                 // < bf16 max finite (3.3895e38)
#define XSTR 136                              // LDS row stride (bf16); 272B keeps b128 align

typedef unsigned short ushort_t;
typedef unsigned int   uint_t;
typedef short   short8   __attribute__((ext_vector_type(8)));
typedef float   floatx16 __attribute__((ext_vector_type(16)));

__device__ __forceinline__ float elu_fast(float v) {   // bf16-accurate ELU
    return v > 0.f ? v : (__expf(v) - 1.f);
}
__device__ __forceinline__ float bf2f(ushort_t h) {
    union { uint_t u; float f; } v; v.u = ((uint_t)h) << 16; return v.f;
}
__device__ __forceinline__ ushort_t f2bf(float f) {   // round-to-nearest-even
    union { float f; uint_t u; } v; v.f = f;
    uint_t r = v.u + 0x7FFFu + ((v.u >> 16) & 1u);
    return (ushort_t)(r >> 16);
}
__device__ __forceinline__ uint_t pkbf(float a, float b) {  // v_cvt_pk_bf16_f32
    union { __hip_bfloat162 h; uint_t u; } v;
    v.h = __float22bfloat162_rn(make_float2(a, b));
    return v.u;
}
__device__ __forceinline__ void unpack2(uint_t u, float& a, float& b) {
    union { uint_t x; float f; } lo, hi;
    lo.x = u << 16; hi.x = u & 0xFFFF0000u;
    a = lo.f; b = hi.f;
}
__device__ __forceinline__ void unpack8(uint4 v, float* f) {
    unpack2(v.x, f[0], f[1]); unpack2(v.y, f[2], f[3]);
    unpack2(v.z, f[4], f[5]); unpack2(v.w, f[6], f[7]);
}
__device__ __forceinline__ void unpack4(uint2 v, float* f) {
    unpack2(v.x, f[0], f[1]); unpack2(v.y, f[2], f[3]);
}

// ---------------------------------------------------------------------------
// Setup: pack LAYER-1 MFMA B-fragments (4096 groups) + zero s0/s1 sum buffers
// (2 x 128 x 128 f32 = 32768 floats). 32 blocks x 256 threads.
// ---------------------------------------------------------------------------
__global__ __launch_bounds__(256) void setup_kernel(
    const ushort_t* __restrict__ Ws,   // 3 x 128 x 128, k-major (layer 0 used)
    const ushort_t* __restrict__ Wn,
    ushort_t* __restrict__ wfrag,
    float* __restrict__ s0s1)
{
    const int g = blockIdx.x * 256 + threadIdx.x;   // 8192 threads
    if (g < 4096) {
        const int lane = g & 63;
        const int ks   = (g >> 6) & 7;
        const int nt   = (g >> 9) & 3;
        const int p    = (g >> 11) & 1;
        const ushort_t* W = p ? Wn : Ws;            // layer 0
        const int k0  = ks * 16 + (lane >> 5) * 8;
        const int col = nt * 32 + (lane & 31);
        ushort_t v[8];
        #pragma unroll
        for (int j = 0; j < 8; ++j) v[j] = W[(size_t)(k0 + j) * FD + col];
        uint4 u;
        u.x = v[0] | ((uint_t)v[1] << 16); u.y = v[2] | ((uint_t)v[3] << 16);
        u.z = v[4] | ((uint_t)v[5] << 16); u.w = v[6] | ((uint_t)v[7] << 16);
        *(uint4*)(wfrag + (size_t)g * 8) = u;
    } else {
        const int idx = g - 4096;                   // 4096 threads x 8 floats
        float4 z = make_float4(0.f, 0.f, 0.f, 0.f);
        *(float4*)(s0s1 + (size_t)idx * 8)     = z;
        *(float4*)(s0s1 + (size_t)idx * 8 + 4) = z;
    }
}

// ---------------------------------------------------------------------------
// GNN layer 1 (full grid) — proven R0 row-pair structure (no meta task,
// meta input = 0), plus two per-block reductions accumulated atomically:
//   s0[b][f] = sum over cells of x0      (feeds meta1 = x1[meta])
//   s1[b][f] = sum over cells of x1 f32  (feeds meta2 = x2[meta])
// 2048 blocks (16/batch, XCD-swizzled) x 256 threads, LDS 34.8 KB.
// ---------------------------------------------------------------------------
__global__ __launch_bounds__(256, 4) void gnn_layer1(
    const ushort_t* __restrict__ xprev,   // gmap, B x 1024 x 128
    ushort_t* __restrict__ xnext,         // x1,   B x 1025 x 128 (meta row unused)
    const ushort_t* __restrict__ wfrag_layer,
    const ushort_t* __restrict__ bs,
    float* __restrict__ s0,
    float* __restrict__ s1)
{
    const int i = blockIdx.x;
    const int xcd = i & 7;
    const int j = i >> 3;                  // 0..255
    const int b = xcd * 16 + (j >> 4);
    const int rb = j & 15;
    const int t = threadIdx.x;
    const ushort_t* xb = xprev + (size_t)b * (NCELL * FD);
    ushort_t* yb = xnext + (size_t)b * (NTOT * FD);

    __shared__ alignas(16) ushort_t xt[64 * XSTR];   // x tile / out tile
    __shared__ alignas(16) ushort_t at[64 * XSTR];   // agg tile / f32 scratch

    const int r0 = rb * 2;

    // Phase 0: issue ALL global loads (main tile + halo rows).
    const ushort_t* src = xb + (size_t)(r0 * SGRID) * FD;
    uint4 mainT[4], haloT[4];
    const uint4 zero4 = make_uint4(0u, 0u, 0u, 0u);
    #pragma unroll
    for (int jj = 0; jj < 4; ++jj) {
        const int e8 = (t + 256 * jj) * 8;     // 0..8184
        const int cc = e8 >> 7, k = e8 & 127;
        const int rr = cc >> 5, c = cc & 31;
        mainT[jj] = *(const uint4*)(src + e8);
        const int grow = (rr == 0) ? (r0 - 1) : (r0 + 2);
        haloT[jj] = (grow >= 0 && grow < SGRID)
            ? *(const uint4*)(xb + (size_t)(grow * SGRID + c) * FD + k) : zero4;
    }
    #pragma unroll
    for (int jj = 0; jj < 4; ++jj) {
        const int e8 = (t + 256 * jj) * 8;
        const int cc = e8 >> 7, k = e8 & 127;
        *(uint4*)&xt[cc * XSTR + k] = mainT[jj];
    }
    // s0 partials from mainT: thread covers cells {t>>4 + 16jj}, feats 8(t&15)..+8
    {
        float sp[8];
        #pragma unroll
        for (int q = 0; q < 8; ++q) sp[q] = 0.f;
        #pragma unroll
        for (int jj = 0; jj < 4; ++jj) {
            float f[8]; unpack8(mainT[jj], f);
            #pragma unroll
            for (int q = 0; q < 8; ++q) sp[q] += f[q];
        }
        float* atF = (float*)at;               // [16][128] f32 scratch
        const int base = (t >> 4) * 128 + (t & 15) * 8;
        #pragma unroll
        for (int q = 0; q < 8; ++q) atF[base + q] = sp[q];
    }
    __syncthreads();
    if (t < 128) {
        const float* atF = (const float*)at;
        float s = 0.f;
        #pragma unroll
        for (int gI = 0; gI < 16; ++gI) s += atF[gI * 128 + t];
        atomicAdd(&s0[b * 128 + t], s);
    }
    __syncthreads();   // atF reads done -> agg phase may overwrite at

    // Build agg tile (bf16): laterals + inner vertical from LDS; halo from regs.
    #pragma unroll
    for (int jj = 0; jj < 4; ++jj) {
        const int e8 = (t + 256 * jj) * 8;
        const int cc = e8 >> 7, k = e8 & 127;
        const int c = cc & 31;
        float s[8];
        unpack8(*(const uint4*)&xt[(cc ^ 32) * XSTR + k], s);   // inner vertical
        if (c > 0) {
            float f[8]; unpack8(*(const uint4*)&xt[(cc - 1) * XSTR + k], f);
            #pragma unroll
            for (int q = 0; q < 8; ++q) s[q] += f[q];
        }
        if (c < 31) {
            float f[8]; unpack8(*(const uint4*)&xt[(cc + 1) * XSTR + k], f);
            #pragma unroll
            for (int q = 0; q < 8; ++q) s[q] += f[q];
        }
        {
            float f[8]; unpack8(haloT[jj], f);
            #pragma unroll
            for (int q = 0; q < 8; ++q) s[q] += f[q];
        }
        uint4 u;
        u.x = pkbf(s[0], s[1]); u.y = pkbf(s[2], s[3]);
        u.z = pkbf(s[4], s[5]); u.w = pkbf(s[6], s[7]);
        *(uint4*)&at[cc * XSTR + k] = u;
    }
    __syncthreads();

    // MFMA GEMM: M=64 (2 m-tiles) x N=128 (4 waves) x K=256.
    const int w = t >> 6;
    const int l = t & 63;
    const int m0 = l & 31;
    const int koff = (l >> 5) * 8;

    floatx16 acc0, acc1;
    #pragma unroll
    for (int q = 0; q < 16; ++q) { acc0[q] = 0.f; acc1[q] = 0.f; }

    #pragma unroll
    for (int p = 0; p < 2; ++p) {
        const ushort_t* X = p ? at : xt;
        const ushort_t* WF = wfrag_layer + (size_t)((p * 4 + w) * 8) * 64 * 8;
        #pragma unroll
        for (int ks = 0; ks < 8; ++ks) {
            const short8 bfrag = *(const short8*)(WF + (size_t)(ks * 64 + l) * 8);
            const short8 av0 = *(const short8*)&xt[0];   // placeholder, replaced below
            (void)av0;
            const short8 a0 = *(const short8*)&X[m0 * XSTR + ks * 16 + koff];
            const short8 a1 = *(const short8*)&X[(m0 + 32) * XSTR + ks * 16 + koff];
            acc0 = __builtin_amdgcn_mfma_f32_32x32x16_bf16(a0, bfrag, acc0, 0, 0, 0);
            acc1 = __builtin_amdgcn_mfma_f32_32x32x16_bf16(a1, bfrag, acc1, 0, 0, 0);
        }
    }
    __syncthreads();   // all waves done reading xt/at

    // Epilogue: bias + elu -> LDS out tile; per-col f32 sums -> at scratch.
    // C/D map: col=lane&31, row=(reg&3)+8*(reg>>2)+4*(lane>>5).
    const int col = w * 32 + (l & 31);
    const float bias = bf2f(bs[col]);
    float colsum = 0.f;
    #pragma unroll
    for (int mt = 0; mt < 2; ++mt) {
        const floatx16 A = mt ? acc1 : acc0;
        #pragma unroll
        for (int r = 0; r < 16; ++r) {
            const int rowC = (r & 3) + 8 * (r >> 2) + 4 * (l >> 5);
            const float v = elu_fast(A[r] + bias);
            colsum += v;
            xt[(mt * 32 + rowC) * XSTR + col] = f2bf(v);
        }
    }
    ((float*)at)[col * 2 + (l >> 5)] = colsum;
    __syncthreads();
    if (t < 128) {
        const float* atF = (const float*)at;
        atomicAdd(&s1[b * 128 + t], atF[t * 2] + atF[t * 2 + 1]);
    }
    ushort_t* dst = yb + (size_t)(r0 * SGRID) * FD;
    #pragma unroll
    for (int jj = 0; jj < 4; ++jj) {
        const int e8 = (t + 256 * jj) * 8;
        const int cc = e8 >> 7, k = e8 & 127;
        *(uint4*)(dst + e8) = *(const uint4*)&xt[cc * XSTR + k];
    }
}

// ---------------------------------------------------------------------------
// Head: per batch, compute meta1/meta2 from s0/s1, recompute layer-2 on a
// 5x5 window and layer-3 on the 5 plus-cells, then the 6-layer MLP + mask.
// 128 blocks (XCD-swizzled, 1 batch) x 1024 threads. LDS ~89 KB.
// ---------------------------------------------------------------------------
__global__ __launch_bounds__(1024) void head_kernel(
    const ushort_t* __restrict__ x1g,     // bf16, B x 1025 x 128 (layer-1 out)
    const int* __restrict__ pos,
    const int* __restrict__ amask,
    const ushort_t* __restrict__ Ws,      // 3 x 128 x 128 (layers 2,3 used)
    const ushort_t* __restrict__ Wn,
    const ushort_t* __restrict__ bs,      // 3 x 128
    const float* __restrict__ s0,
    const float* __restrict__ s1,
    const ushort_t* __restrict__ Wd1, const ushort_t* __restrict__ bd1,
    const ushort_t* __restrict__ Wd2, const ushort_t* __restrict__ bd2,
    const ushort_t* __restrict__ Wd3, const ushort_t* __restrict__ bd3,
    const ushort_t* __restrict__ Wp1, const ushort_t* __restrict__ bp1,
    const ushort_t* __restrict__ Wp2, const ushort_t* __restrict__ bp2,
    const ushort_t* __restrict__ Wp3, const ushort_t* __restrict__ bp3,
    ushort_t* __restrict__ out)           // bf16, B x 19
{
    const int t = threadIdx.x;
    const int b = (blockIdx.x & 7) * 16 + (blockIdx.x >> 3);
    const int f = t & 127;
    const int g = t >> 7;                  // 0..7
    const int q = t >> 6;                  // wave 0..15
    const int lane = t & 63;

    __shared__ float x1w[49 * 128];        // 7x7 window of x1, f32, zero-padded
    __shared__ float aggv[25 * 128];       // layer-2 agg / later layer-3 agg
    __shared__ float x2w[25 * 128];        // layer-2 outputs on 5x5 window
    __shared__ float m1[128], m2[128];     // meta1 = x1[meta], meta2 = x2[meta]
    __shared__ float st[640];
    __shared__ float bufA[512];
    __shared__ float bufB[512];
    __shared__ float part[16][512];

    const int pr = pos[b * 2 + 0], pc = pos[b * 2 + 1];
    const ushort_t* Ws2 = Ws + FD * FD;
    const ushort_t* Wn2 = Wn + FD * FD;
    const ushort_t* Ws3 = Ws + 2 * FD * FD;
    const ushort_t* Wn3 = Wn + 2 * FD * FD;

    // ---- Phase 1: load 7x7 x1 window (zero outside grid); meta1 ----
    for (int wi = g; wi < 49; wi += 8) {
        const int r = pr + wi / 7 - 3, c = pc + wi % 7 - 3;
        float v = 0.f;
        if (r >= 0 && r < SGRID && c >= 0 && c < SGRID)
            v = bf2f(x1g[((size_t)b * NTOT + r * SGRID + c) * FD + f]);
        x1w[wi * 128 + f] = v;
    }
    if (t < 128) {   // meta1 = elu(b1 + s0 @ Wn1)   (x0[meta] = 0)
        float a = bf2f(bs[t]);
        #pragma unroll 4
        for (int k = 0; k < 128; ++k)
            a += s0[b * 128 + k] * bf2f(Wn[k * FD + t]);
        m1[t] = elu_fast(a);
    }
    __syncthreads();

    // ---- Phase 2: layer-2 agg vectors on 5x5 window; meta2 ----
    #pragma unroll
    for (int jj = 0; jj < 4; ++jj) {
        const int ci = g + 8 * jj;
        if (ci < 25) {
            const int wi = (ci / 5 + 1) * 7 + (ci % 5 + 1);
            aggv[ci * 128 + f] = x1w[(wi - 7) * 128 + f] + x1w[(wi + 7) * 128 + f]
                               + x1w[(wi - 1) * 128 + f] + x1w[(wi + 1) * 128 + f]
                               + m1[f];
        }
    }
    if (t < 128) {   // meta2 = elu(b2 + m1 @ Ws2 + s1 @ Wn2)
        float a = bf2f(bs[FD + t]);
        #pragma unroll 4
        for (int k = 0; k < 128; ++k)
            a += m1[k] * bf2f(Ws2[k * FD + t]) + s1[b * 128 + k] * bf2f(Wn2[k * FD + t]);
        m2[t] = elu_fast(a);
    }
    __syncthreads();

    // ---- Phase 3: layer-2 outputs on 5x5 window ----
    {
        float acc[4];
        int wis[4], cis[4];
        #pragma unroll
        for (int jj = 0; jj < 4; ++jj) {
            const int ci = g + 8 * jj;
            cis[jj] = (ci < 25) ? ci : 24;
            wis[jj] = (cis[jj] / 5 + 1) * 7 + (cis[jj] % 5 + 1);
            acc[jj] = 0.f;
        }
        #pragma unroll 2
        for (int k = 0; k < 128; ++k) {
            const float ws2 = bf2f(Ws2[k * FD + f]);
            const float wn2 = bf2f(Wn2[k * FD + f]);
            #pragma unroll
            for (int jj = 0; jj < 4; ++jj)
                acc[jj] += x1w[wis[jj] * 128 + k] * ws2 + aggv[cis[jj] * 128 + k] * wn2;
        }
        const float b2 = bf2f(bs[FD + f]);
        #pragma unroll
        for (int jj = 0; jj < 4; ++jj) {
            const int ci = g + 8 * jj;
            if (ci < 25) x2w[ci * 128 + f] = elu_fast(acc[jj] + b2);
        }
    }
    __syncthreads();

    // ---- Phase 4: layer-3 agg for the 5 plus-cells (in-grid masked) ----
    const int OR_ = (g == 0) ? -1 : ((g == 2) ? 1 : 0);
    const int OC_ = (g == 1) ? -1 : ((g == 3) ? 1 : 0);
    if (g < 5) {
        const int r3 = pr + OR_, c3 = pc + OC_;
        float a = m2[f];
        const int DR[4] = {-1, 1, 0, 0};
        const int DC[4] = {0, 0, -1, 1};
        #pragma unroll
        for (int d = 0; d < 4; ++d) {
            const int rn = r3 + DR[d], cn = c3 + DC[d];
            if (rn >= 0 && rn < SGRID && cn >= 0 && cn < SGRID) {
                const int cin = (OR_ + DR[d] + 2) * 5 + (OC_ + DC[d] + 2);
                a += x2w[cin * 128 + f];
            }
        }
        aggv[g * 128 + f] = a;   // reuse aggv as layer-3 agg
    }
    __syncthreads();

    // ---- Phase 5: layer-3 outputs -> st[640] (zero for out-of-grid slots) ----
    if (g < 5) {
        const int r3 = pr + OR_, c3 = pc + OC_;
        const int cig = (OR_ + 2) * 5 + (OC_ + 2);
        float a = bf2f(bs[2 * FD + f]);
        #pragma unroll 2
        for (int k = 0; k < 128; ++k)
            a += x2w[cig * 128 + k] * bf2f(Ws3[k * FD + f])
               + aggv[g * 128 + k]  * bf2f(Wn3[k * FD + f]);
        const bool ig = (r3 >= 0 && r3 < SGRID && c3 >= 0 && c3 < SGRID);
        st[g * 128 + f] = ig ? elu_fast(a) : 0.f;
    }
    __syncthreads();

    // ---- L1: 640 -> 512 (K/16 = 40 per wave; lane owns 8 cols) ----
    {
        float acc[8];
        #pragma unroll
        for (int p = 0; p < 8; ++p) acc[p] = 0.f;
        const int c0 = lane * 8;
        const int kb = q * 40;
        #pragma unroll 8
        for (int k = kb; k < kb + 40; ++k) {
            const float s = st[k];
            float fv[8]; unpack8(*(const uint4*)(Wd1 + (size_t)k * 512 + c0), fv);
            #pragma unroll
            for (int p = 0; p < 8; ++p) acc[p] += s * fv[p];
        }
        #pragma unroll
        for (int p = 0; p < 8; ++p) part[q][c0 + p] = acc[p];
        __syncthreads();
        if (t < 512) {
            float a = bf2f(bd1[t]);
            #pragma unroll
            for (int p = 0; p < 16; ++p) a += part[p][t];
            bufA[t] = elu_fast(a);
        }
        __syncthreads();
    }
    // ---- L2: 512 -> 512 (K/16 = 32) ----
    {
        float acc[8];
        #pragma unroll
        for (int p = 0; p < 8; ++p) acc[p] = 0.f;
        const int c0 = lane * 8;
        const int kb = q * 32;
        #pragma unroll 8
        for (int k = kb; k < kb + 32; ++k) {
            const float s = bufA[k];
            float fv[8]; unpack8(*(const uint4*)(Wd2 + (size_t)k * 512 + c0), fv);
            #pragma unroll
            for (int p = 0; p < 8; ++p) acc[p] += s * fv[p];
        }
        #pragma unroll
        for (int p = 0; p < 8; ++p) part[q][c0 + p] = acc[p];
        __syncthreads();
        if (t < 512) {
            float a = bf2f(bd2[t]);
            #pragma unroll
            for (int p = 0; p < 16; ++p) a += part[p][t];
            bufB[t] = elu_fast(a);
        }
        __syncthreads();
    }
    // ---- L3: 512 -> 256 (K/16 = 32; out -> st[0..255]) ----
    {
        float acc[4];
        #pragma unroll
        for (int p = 0; p < 4; ++p) acc[p] = 0.f;
        const int c0 = lane * 4;
        const int kb = q * 32;
        #pragma unroll 8
        for (int k = kb; k < kb + 32; ++k) {
            const float s = bufB[k];
            float fv[4]; unpack4(*(const uint2*)(Wd3 + (size_t)k * 256 + c0), fv);
            #pragma unroll
            for (int p = 0; p < 4; ++p) acc[p] += s * fv[p];
        }
        #pragma unroll
        for (int p = 0; p < 4; ++p) part[q][c0 + p] = acc[p];
        __syncthreads();
        if (t < 256) {
            float a = bf2f(bd3[t]);
            #pragma unroll
            for (int p = 0; p < 16; ++p) a += part[p][t];
            st[t] = elu_fast(a);
        }
        __syncthreads();
    }
    // ---- L4: 256 -> 256 (K/16 = 16; st -> bufA) ----
    {
        float acc[4];
        #pragma unroll
        for (int p = 0; p < 4; ++p) acc[p] = 0.f;
        const int c0 = lane * 4;
        const int kb = q * 16;
        #pragma unroll 8
        for (int k = kb; k < kb + 16; ++k) {
            const float s = st[k];
            float fv[4]; unpack4(*(const uint2*)(Wp1 + (size_t)k * 256 + c0), fv);
            #pragma unroll
            for (int p = 0; p < 4; ++p) acc[p] += s * fv[p];
        }
        #pragma unroll
        for (int p = 0; p < 4; ++p) part[q][c0 + p] = acc[p];
        __syncthreads();
        if (t < 256) {
            float a = bf2f(bp1[t]);
            #pragma unroll
            for (int p = 0; p < 16; ++p) a += part[p][t];
            bufA[t] = elu_fast(a);
        }
        __syncthreads();
    }
    // ---- L5: 256 -> 256 (bufA -> bufB) ----
    {
        float acc[4];
        #pragma unroll
        for (int p = 0; p < 4; ++p) acc[p] = 0.f;
        const int c0 = lane * 4;
        const int kb = q * 16;
        #pragma unroll 8
        for (int k = kb; k < kb + 16; ++k) {
            const float s = bufA[k];
            float fv[4]; unpack4(*(const uint2*)(Wp2 + (size_t)k * 256 + c0), fv);
            #pragma unroll
            for (int p = 0; p < 4; ++p) acc[p] += s * fv[p];
        }
        #pragma unroll
        for (int p = 0; p < 4; ++p) part[q][c0 + p] = acc[p];
        __syncthreads();
        if (t < 256) {
            float a = bf2f(bp2[t]);
            #pragma unroll
            for (int p = 0; p < 16; ++p) a += part[p][t];
            bufB[t] = elu_fast(a);
        }
        __syncthreads();
    }
    // ---- L6: 256 -> 19 + mask, finite-clamped bf16 ----
    {
        float a = 0.f;
        const int kb = q * 16;
        if (lane < NACT) {
            #pragma unroll 8
            for (int k = kb; k < kb + 16; ++k)
                a += bufB[k] * bf2f(Wp3[(size_t)k * NACT + lane]);
            part[q][lane] = a;
        }
        __syncthreads();
        if (t < NACT) {
            float v = bf2f(bp3[t]);
            #pragma unroll
            for (int p = 0; p < 16; ++p) v += part[p][t];
            v += amask[b * NACT + t] ? 0.f : NEG_INF_F;
            v = fminf(fmaxf(v, -BF16_SAFE_F), BF16_SAFE_F);
            out[b * NACT + t] = f2bf(v);
        }
    }
}

extern "C" void kernel_launch(void* const* d_in, const int* in_sizes, int n_in,
                              void* d_out, int out_size, void* d_ws, size_t ws_size,
                              hipStream_t stream) {
    const ushort_t* gmap  = (const ushort_t*)d_in[0];
    const int*      pos   = (const int*)     d_in[1];
    const int*      amask = (const int*)     d_in[2];
    const ushort_t* Ws    = (const ushort_t*)d_in[3];
    const ushort_t* Wn    = (const ushort_t*)d_in[4];
    const ushort_t* bs    = (const ushort_t*)d_in[5];
    const ushort_t* Wd1   = (const ushort_t*)d_in[6];
    const ushort_t* bd1   = (const ushort_t*)d_in[7];
    const ushort_t* Wd2   = (const ushort_t*)d_in[8];
    const ushort_t* bd2   = (const ushort_t*)d_in[9];
    const ushort_t* Wd3   = (const ushort_t*)d_in[10];
    const ushort_t* bd3   = (const ushort_t*)d_in[11];
    const ushort_t* Wp1   = (const ushort_t*)d_in[12];
    const ushort_t* bp1   = (const ushort_t*)d_in[13];
    const ushort_t* Wp2   = (const ushort_t*)d_in[14];
    const ushort_t* bp2   = (const ushort_t*)d_in[15];
    const ushort_t* Wp3   = (const ushort_t*)d_in[16];
    const ushort_t* bp3   = (const ushort_t*)d_in[17];

    // Workspace: x1 (33.6 MB) + layer-1 frags (64 KB) + s0/s1 (128 KB).
    ushort_t* x1 = (ushort_t*)d_ws;
    ushort_t* wfrag = x1 + (size_t)BATCH * NTOT * FD;
    float* s0s1 = (float*)(wfrag + 4096 * 8);
    float* s0 = s0s1;
    float* s1 = s0s1 + BATCH * FD;

    setup_kernel<<<32, 256, 0, stream>>>(Ws, Wn, wfrag, s0s1);

    gnn_layer1<<<16 * BATCH, 256, 0, stream>>>(gmap, x1, wfrag, bs, s0, s1);

    head_kernel<<<BATCH, 1024, 0, stream>>>(x1, pos, amask,
                                            Ws, Wn, bs, s0, s1,
                                            Wd1, bd1, Wd2, bd2, Wd3, bd3,
                                            Wp1, bp1, Wp2, bp2, Wp3, bp3,
                                            (ushort_t*)d_out);
}

// Round 7
// 206.941 us; speedup vs baseline: 3.1744x; 1.0928x over previous
//
#include <hip/hip_runtime.h>
#include <hip/hip_bf16.h>

#define BATCH 128
#define SGRID 32
#define NCELL 1024
#define NTOT  1025
#define FD    128
#define NACT  19
#define NEG_INF_F  (-3.4028234663852886e38f)  // jnp.finfo(float32).min
#define BF16_SAFE_F (3.3e38f)                 // < bf16 max finite (3.3895e38)
#define XSTR 136                              // LDS row stride (bf16); 272B keeps b128 align

typedef unsigned short ushort_t;
typedef unsigned int   uint_t;
typedef short   short8   __attribute__((ext_vector_type(8)));
typedef float   floatx16 __attribute__((ext_vector_type(16)));

__device__ __forceinline__ float elu_fast(float v) {   // bf16-accurate ELU
    return v > 0.f ? v : (__expf(v) - 1.f);
}
__device__ __forceinline__ float bf2f(ushort_t h) {
    union { uint_t u; float f; } v; v.u = ((uint_t)h) << 16; return v.f;
}
__device__ __forceinline__ ushort_t f2bf(float f) {   // round-to-nearest-even
    union { float f; uint_t u; } v; v.f = f;
    uint_t r = v.u + 0x7FFFu + ((v.u >> 16) & 1u);
    return (ushort_t)(r >> 16);
}
__device__ __forceinline__ uint_t pkbf(float a, float b) {  // v_cvt_pk_bf16_f32
    union { __hip_bfloat162 h; uint_t u; } v;
    v.h = __float22bfloat162_rn(make_float2(a, b));
    return v.u;
}
__device__ __forceinline__ void unpack2(uint_t u, float& a, float& b) {
    union { uint_t x; float f; } lo, hi;
    lo.x = u << 16; hi.x = u & 0xFFFF0000u;
    a = lo.f; b = hi.f;
}
__device__ __forceinline__ void unpack8(uint4 v, float* f) {
    unpack2(v.x, f[0], f[1]); unpack2(v.y, f[2], f[3]);
    unpack2(v.z, f[4], f[5]); unpack2(v.w, f[6], f[7]);
}
__device__ __forceinline__ void unpack4(uint2 v, float* f) {
    unpack2(v.x, f[0], f[1]); unpack2(v.y, f[2], f[3]);
}

// ---------------------------------------------------------------------------
// Setup: pack LAYER-1 MFMA B-fragments (4096 groups) + zero s0/s1 sum buffers.
// ---------------------------------------------------------------------------
__global__ __launch_bounds__(256) void setup_kernel(
    const ushort_t* __restrict__ Ws,   // 3 x 128 x 128, k-major (layer 0 used)
    const ushort_t* __restrict__ Wn,
    ushort_t* __restrict__ wfrag,
    float* __restrict__ s0s1)
{
    const int g = blockIdx.x * 256 + threadIdx.x;   // 8192 threads
    if (g < 4096) {
        const int lane = g & 63;
        const int ks   = (g >> 6) & 7;
        const int nt   = (g >> 9) & 3;
        const int p    = (g >> 11) & 1;
        const ushort_t* W = p ? Wn : Ws;            // layer 0
        const int k0  = ks * 16 + (lane >> 5) * 8;
        const int col = nt * 32 + (lane & 31);
        ushort_t v[8];
        #pragma unroll
        for (int j = 0; j < 8; ++j) v[j] = W[(size_t)(k0 + j) * FD + col];
        uint4 u;
        u.x = v[0] | ((uint_t)v[1] << 16); u.y = v[2] | ((uint_t)v[3] << 16);
        u.z = v[4] | ((uint_t)v[5] << 16); u.w = v[6] | ((uint_t)v[7] << 16);
        *(uint4*)(wfrag + (size_t)g * 8) = u;
    } else {
        const int idx = g - 4096;                   // 4096 threads x 8 floats
        float4 z = make_float4(0.f, 0.f, 0.f, 0.f);
        *(float4*)(s0s1 + (size_t)idx * 8)     = z;
        *(float4*)(s0s1 + (size_t)idx * 8 + 4) = z;
    }
}

// ---------------------------------------------------------------------------
// GNN layer 1 (full grid) — proven row-pair structure + atomic s0/s1 sums.
// ---------------------------------------------------------------------------
__global__ __launch_bounds__(256, 4) void gnn_layer1(
    const ushort_t* __restrict__ xprev,   // gmap, B x 1024 x 128
    ushort_t* __restrict__ xnext,         // x1,   B x 1025 x 128 (meta row unused)
    const ushort_t* __restrict__ wfrag_layer,
    const ushort_t* __restrict__ bs,
    float* __restrict__ s0,
    float* __restrict__ s1)
{
    const int i = blockIdx.x;
    const int xcd = i & 7;
    const int j = i >> 3;                  // 0..255
    const int b = xcd * 16 + (j >> 4);
    const int rb = j & 15;
    const int t = threadIdx.x;
    const ushort_t* xb = xprev + (size_t)b * (NCELL * FD);
    ushort_t* yb = xnext + (size_t)b * (NTOT * FD);

    __shared__ alignas(16) ushort_t xt[64 * XSTR];   // x tile / out tile
    __shared__ alignas(16) ushort_t at[64 * XSTR];   // agg tile / f32 scratch

    const int r0 = rb * 2;

    const ushort_t* src = xb + (size_t)(r0 * SGRID) * FD;
    uint4 mainT[4], haloT[4];
    const uint4 zero4 = make_uint4(0u, 0u, 0u, 0u);
    #pragma unroll
    for (int jj = 0; jj < 4; ++jj) {
        const int e8 = (t + 256 * jj) * 8;     // 0..8184
        const int cc = e8 >> 7, k = e8 & 127;
        const int rr = cc >> 5, c = cc & 31;
        mainT[jj] = *(const uint4*)(src + e8);
        const int grow = (rr == 0) ? (r0 - 1) : (r0 + 2);
        haloT[jj] = (grow >= 0 && grow < SGRID)
            ? *(const uint4*)(xb + (size_t)(grow * SGRID + c) * FD + k) : zero4;
    }
    #pragma unroll
    for (int jj = 0; jj < 4; ++jj) {
        const int e8 = (t + 256 * jj) * 8;
        const int cc = e8 >> 7, k = e8 & 127;
        *(uint4*)&xt[cc * XSTR + k] = mainT[jj];
    }
    // s0 partials from mainT.
    {
        float sp[8];
        #pragma unroll
        for (int q = 0; q < 8; ++q) sp[q] = 0.f;
        #pragma unroll
        for (int jj = 0; jj < 4; ++jj) {
            float f[8]; unpack8(mainT[jj], f);
            #pragma unroll
            for (int q = 0; q < 8; ++q) sp[q] += f[q];
        }
        float* atF = (float*)at;               // [16][128] f32 scratch
        const int base = (t >> 4) * 128 + (t & 15) * 8;
        #pragma unroll
        for (int q = 0; q < 8; ++q) atF[base + q] = sp[q];
    }
    __syncthreads();
    if (t < 128) {
        const float* atF = (const float*)at;
        float s = 0.f;
        #pragma unroll
        for (int gI = 0; gI < 16; ++gI) s += atF[gI * 128 + t];
        atomicAdd(&s0[b * 128 + t], s);
    }
    __syncthreads();   // atF reads done -> agg phase may overwrite at

    // Build agg tile (bf16).
    #pragma unroll
    for (int jj = 0; jj < 4; ++jj) {
        const int e8 = (t + 256 * jj) * 8;
        const int cc = e8 >> 7, k = e8 & 127;
        const int c = cc & 31;
        float s[8];
        unpack8(*(const uint4*)&xt[(cc ^ 32) * XSTR + k], s);   // inner vertical
        if (c > 0) {
            float f[8]; unpack8(*(const uint4*)&xt[(cc - 1) * XSTR + k], f);
            #pragma unroll
            for (int q = 0; q < 8; ++q) s[q] += f[q];
        }
        if (c < 31) {
            float f[8]; unpack8(*(const uint4*)&xt[(cc + 1) * XSTR + k], f);
            #pragma unroll
            for (int q = 0; q < 8; ++q) s[q] += f[q];
        }
        {
            float f[8]; unpack8(haloT[jj], f);
            #pragma unroll
            for (int q = 0; q < 8; ++q) s[q] += f[q];
        }
        uint4 u;
        u.x = pkbf(s[0], s[1]); u.y = pkbf(s[2], s[3]);
        u.z = pkbf(s[4], s[5]); u.w = pkbf(s[6], s[7]);
        *(uint4*)&at[cc * XSTR + k] = u;
    }
    __syncthreads();

    // MFMA GEMM: M=64 x N=128 x K=256.
    const int w = t >> 6;
    const int l = t & 63;
    const int m0 = l & 31;
    const int koff = (l >> 5) * 8;

    floatx16 acc0, acc1;
    #pragma unroll
    for (int q = 0; q < 16; ++q) { acc0[q] = 0.f; acc1[q] = 0.f; }

    #pragma unroll
    for (int p = 0; p < 2; ++p) {
        const ushort_t* X = p ? at : xt;
        const ushort_t* WF = wfrag_layer + (size_t)((p * 4 + w) * 8) * 64 * 8;
        #pragma unroll
        for (int ks = 0; ks < 8; ++ks) {
            const short8 bfrag = *(const short8*)(WF + (size_t)(ks * 64 + l) * 8);
            const short8 a0 = *(const short8*)&X[m0 * XSTR + ks * 16 + koff];
            const short8 a1 = *(const short8*)&X[(m0 + 32) * XSTR + ks * 16 + koff];
            acc0 = __builtin_amdgcn_mfma_f32_32x32x16_bf16(a0, bfrag, acc0, 0, 0, 0);
            acc1 = __builtin_amdgcn_mfma_f32_32x32x16_bf16(a1, bfrag, acc1, 0, 0, 0);
        }
    }
    __syncthreads();

    // Epilogue: bias + elu -> LDS out tile; per-col f32 sums -> at scratch.
    const int col = w * 32 + (l & 31);
    const float bias = bf2f(bs[col]);
    float colsum = 0.f;
    #pragma unroll
    for (int mt = 0; mt < 2; ++mt) {
        const floatx16 A = mt ? acc1 : acc0;
        #pragma unroll
        for (int r = 0; r < 16; ++r) {
            const int rowC = (r & 3) + 8 * (r >> 2) + 4 * (l >> 5);
            const float v = elu_fast(A[r] + bias);
            colsum += v;
            xt[(mt * 32 + rowC) * XSTR + col] = f2bf(v);
        }
    }
    ((float*)at)[col * 2 + (l >> 5)] = colsum;
    __syncthreads();
    if (t < 128) {
        const float* atF = (const float*)at;
        atomicAdd(&s1[b * 128 + t], atF[t * 2] + atF[t * 2 + 1]);
    }
    ushort_t* dst = yb + (size_t)(r0 * SGRID) * FD;
    #pragma unroll
    for (int jj = 0; jj < 4; ++jj) {
        const int e8 = (t + 256 * jj) * 8;
        const int cc = e8 >> 7, k = e8 & 127;
        *(uint4*)(dst + e8) = *(const uint4*)&xt[cc * XSTR + k];
    }
}

// ---------------------------------------------------------------------------
// Head windows: 640 blocks (5 per batch = one per plus-cell, XCD-aligned
// with the batch's layer-1 writer) x 256 threads. Per block:
//   m1 = elu(b1 + s0@Wn1); m2 = elu(b2 + m1@Ws2 + s1@Wn2)
//   x2 at the plus-cell's 5-cell diamond; x3 at the plus cell
//   -> stg[b][g*128..] (f32; zero if plus cell out of grid)
// LDS ~12.5 KB, every phase >=128 active threads, ~6 blocks/CU.
// ---------------------------------------------------------------------------
__global__ __launch_bounds__(256) void head_window(
    const ushort_t* __restrict__ x1g,     // bf16, B x 1025 x 128
    const int* __restrict__ pos,
    const ushort_t* __restrict__ Ws,      // 3 x 128 x 128
    const ushort_t* __restrict__ Wn,
    const ushort_t* __restrict__ bs,      // 3 x 128
    const float* __restrict__ s0,
    const float* __restrict__ s1,
    float* __restrict__ stg)              // f32, B x 640
{
    const int xcd = blockIdx.x & 7;
    const int idx = blockIdx.x >> 3;       // 0..79
    const int b = xcd * 16 + idx / 5;
    const int g = idx % 5;
    const int t = threadIdx.x;
    const int f = t & 127;
    const int h = t >> 7;                  // K-half

    // Diamond |dr|+|dc|<=2 around the plus cell P.
    const int D13R[13] = {-2,-1,-1,-1, 0, 0, 0, 0, 0, 1, 1, 1, 2};
    const int D13C[13] = { 0,-1, 0, 1,-2,-1, 0, 1, 2,-1, 0, 1, 0};
    const int C5[5]    = { 2, 5, 6, 7, 9 };           // dist<=1 cells in D13

    __shared__ float x1d[13 * 128];        // 6.5 KB
    __shared__ float x2d[5 * 128];
    __shared__ float aggd[5 * 128];
    __shared__ float m1[128], m2[128], agg3[128];
    __shared__ float part[2][128];

    const int OFFR[5] = {-1, 0, 1, 0, 0};
    const int OFFC[5] = {0, -1, 0, 1, 0};
    const int pr = pos[b * 2 + 0] + OFFR[g];
    const int pc = pos[b * 2 + 1] + OFFC[g];

    const ushort_t* Ws2 = Ws + FD * FD;
    const ushort_t* Wn2 = Wn + FD * FD;
    const ushort_t* Ws3 = Ws + 2 * FD * FD;
    const ushort_t* Wn3 = Wn + 2 * FD * FD;

    // Phase 1: load x1 diamond (zero outside grid).
    for (int e = t; e < 13 * 128; e += 256) {
        const int ci = e >> 7, ff = e & 127;
        const int r = pr + D13R[ci], c = pc + D13C[ci];
        float v = 0.f;
        if (r >= 0 && r < SGRID && c >= 0 && c < SGRID)
            v = bf2f(x1g[((size_t)b * NTOT + r * SGRID + c) * FD + ff]);
        x1d[ci * 128 + ff] = v;
    }
    // Phase 2: m1 (2-way K-split).
    {
        float a = 0.f;
        const int kb = h * 64;
        #pragma unroll 8
        for (int k = kb; k < kb + 64; ++k)
            a += s0[b * 128 + k] * bf2f(Wn[k * FD + f]);
        part[h][f] = a;
    }
    __syncthreads();
    if (t < 128) m1[f] = elu_fast(bf2f(bs[f]) + part[0][f] + part[1][f]);
    __syncthreads();
    // Phase 3: m2.
    {
        float a = 0.f;
        const int kb = h * 64;
        #pragma unroll 4
        for (int k = kb; k < kb + 64; ++k)
            a += m1[k] * bf2f(Ws2[k * FD + f]) + s1[b * 128 + k] * bf2f(Wn2[k * FD + f]);
        part[h][f] = a;
    }
    __syncthreads();
    if (t < 128) m2[f] = elu_fast(bf2f(bs[FD + f]) + part[0][f] + part[1][f]);
    // Phase 4a: agg for the 5 x2 cells (zero-padded x1d makes masking free).
    for (int e = t; e < 5 * 128; e += 256) {
        const int cc = e >> 7, ff = e & 127;
        const int dr = D13R[C5[cc]], dc = D13C[C5[cc]];
        float a = 0.f;
        // neighbor lookup in D13 by (dr,dc): compile-time linear search
        #pragma unroll
        for (int d = 0; d < 4; ++d) {
            const int DR[4] = {-1, 1, 0, 0};
            const int DC[4] = {0, 0, -1, 1};
            const int nr = dr + DR[d], nc = dc + DC[d];
            #pragma unroll
            for (int ci = 0; ci < 13; ++ci)
                if (D13R[ci] == nr && D13C[ci] == nc) a += x1d[ci * 128 + ff];
        }
        aggd[e] = a;
    }
    __syncthreads();
    // add m1 into aggd (m1 is ready after the barrier above)
    for (int e = t; e < 5 * 128; e += 256) aggd[e] += m1[e & 127];
    __syncthreads();
    // Phase 4b: x2 at 5 cells; thread (f,h) covers cells {h, h+2, h+4<5}.
    for (int cc = h; cc < 5; cc += 2) {
        const int ci = C5[cc];
        float a = bf2f(bs[FD + f]);
        #pragma unroll 4
        for (int k = 0; k < 128; ++k)
            a += x1d[ci * 128 + k] * bf2f(Ws2[k * FD + f])
               + aggd[cc * 128 + k] * bf2f(Wn2[k * FD + f]);
        x2d[cc * 128 + f] = elu_fast(a);
    }
    __syncthreads();
    // Phase 5a: agg3 at P (mask out-of-grid neighbors).
    if (t < 128) {
        float a = m2[f];
        const int DR[4] = {-1, 1, 0, 0};
        const int DC[4] = {0, 0, -1, 1};
        const int CCn[4] = {0, 4, 1, 3};   // C5 index of (-1,0),(1,0),(0,-1),(0,1)
        #pragma unroll
        for (int d = 0; d < 4; ++d) {
            const int r = pr + DR[d], c = pc + DC[d];
            if (r >= 0 && r < SGRID && c >= 0 && c < SGRID)
                a += x2d[CCn[d] * 128 + f];
        }
        agg3[f] = a;
    }
    __syncthreads();
    // Phase 5b: x3 at P (2-way K-split), write st slice.
    {
        float a = 0.f;
        const int kb = h * 64;
        #pragma unroll 4
        for (int k = kb; k < kb + 64; ++k)
            a += x2d[2 * 128 + k] * bf2f(Ws3[k * FD + f])
               + agg3[k] * bf2f(Wn3[k * FD + f]);
        part[h][f] = a;
    }
    __syncthreads();
    if (t < 128) {
        const bool ig = (pr >= 0 && pr < SGRID && pc >= 0 && pc < SGRID);
        const float v = elu_fast(bf2f(bs[2 * FD + f]) + part[0][f] + part[1][f]);
        stg[(size_t)b * 640 + g * 128 + f] = ig ? v : 0.f;
    }
}

// ---------------------------------------------------------------------------
// Head MLP: proven 16-wave structure; st comes from workspace.
// 128 blocks (XCD-swizzled, 1 batch each) x 1024 threads.
// ---------------------------------------------------------------------------
__global__ __launch_bounds__(1024) void head_mlp(
    const float* __restrict__ stg,        // f32, B x 640
    const int* __restrict__ amask,
    const ushort_t* __restrict__ Wd1, const ushort_t* __restrict__ bd1,
    const ushort_t* __restrict__ Wd2, const ushort_t* __restrict__ bd2,
    const ushort_t* __restrict__ Wd3, const ushort_t* __restrict__ bd3,
    const ushort_t* __restrict__ Wp1, const ushort_t* __restrict__ bp1,
    const ushort_t* __restrict__ Wp2, const ushort_t* __restrict__ bp2,
    const ushort_t* __restrict__ Wp3, const ushort_t* __restrict__ bp3,
    ushort_t* __restrict__ out)           // bf16, B x 19
{
    const int t = threadIdx.x;
    const int b = (blockIdx.x & 7) * 16 + (blockIdx.x >> 3);
    const int q = t >> 6;             // wave 0..15
    const int lane = t & 63;

    __shared__ float st[640];
    __shared__ float bufA[512];
    __shared__ float bufB[512];
    __shared__ float part[16][512];

    if (t < 640) st[t] = stg[(size_t)b * 640 + t];
    __syncthreads();

    // ---- L1: 640 -> 512 ----
    {
        float acc[8];
        #pragma unroll
        for (int p = 0; p < 8; ++p) acc[p] = 0.f;
        const int c0 = lane * 8;
        const int kb = q * 40;
        #pragma unroll 8
        for (int k = kb; k < kb + 40; ++k) {
            const float s = st[k];
            float fv[8]; unpack8(*(const uint4*)(Wd1 + (size_t)k * 512 + c0), fv);
            #pragma unroll
            for (int p = 0; p < 8; ++p) acc[p] += s * fv[p];
        }
        #pragma unroll
        for (int p = 0; p < 8; ++p) part[q][c0 + p] = acc[p];
        __syncthreads();
        if (t < 512) {
            float a = bf2f(bd1[t]);
            #pragma unroll
            for (int p = 0; p < 16; ++p) a += part[p][t];
            bufA[t] = elu_fast(a);
        }
        __syncthreads();
    }
    // ---- L2: 512 -> 512 ----
    {
        float acc[8];
        #pragma unroll
        for (int p = 0; p < 8; ++p) acc[p] = 0.f;
        const int c0 = lane * 8;
        const int kb = q * 32;
        #pragma unroll 8
        for (int k = kb; k < kb + 32; ++k) {
            const float s = bufA[k];
            float fv[8]; unpack8(*(const uint4*)(Wd2 + (size_t)k * 512 + c0), fv);
            #pragma unroll
            for (int p = 0; p < 8; ++p) acc[p] += s * fv[p];
        }
        #pragma unroll
        for (int p = 0; p < 8; ++p) part[q][c0 + p] = acc[p];
        __syncthreads();
        if (t < 512) {
            float a = bf2f(bd2[t]);
            #pragma unroll
            for (int p = 0; p < 16; ++p) a += part[p][t];
            bufB[t] = elu_fast(a);
        }
        __syncthreads();
    }
    // ---- L3: 512 -> 256 ----
    {
        float acc[4];
        #pragma unroll
        for (int p = 0; p < 4; ++p) acc[p] = 0.f;
        const int c0 = lane * 4;
        const int kb = q * 32;
        #pragma unroll 8
        for (int k = kb; k < kb + 32; ++k) {
            const float s = bufB[k];
            float fv[4]; unpack4(*(const uint2*)(Wd3 + (size_t)k * 256 + c0), fv);
            #pragma unroll
            for (int p = 0; p < 4; ++p) acc[p] += s * fv[p];
        }
        #pragma unroll
        for (int p = 0; p < 4; ++p) part[q][c0 + p] = acc[p];
        __syncthreads();
        if (t < 256) {
            float a = bf2f(bd3[t]);
            #pragma unroll
            for (int p = 0; p < 16; ++p) a += part[p][t];
            st[t] = elu_fast(a);
        }
        __syncthreads();
    }
    // ---- L4: 256 -> 256 ----
    {
        float acc[4];
        #pragma unroll
        for (int p = 0; p < 4; ++p) acc[p] = 0.f;
        const int c0 = lane * 4;
        const int kb = q * 16;
        #pragma unroll 8
        for (int k = kb; k < kb + 16; ++k) {
            const float s = st[k];
            float fv[4]; unpack4(*(const uint2*)(Wp1 + (size_t)k * 256 + c0), fv);
            #pragma unroll
            for (int p = 0; p < 4; ++p) acc[p] += s * fv[p];
        }
        #pragma unroll
        for (int p = 0; p < 4; ++p) part[q][c0 + p] = acc[p];
        __syncthreads();
        if (t < 256) {
            float a = bf2f(bp1[t]);
            #pragma unroll
            for (int p = 0; p < 16; ++p) a += part[p][t];
            bufA[t] = elu_fast(a);
        }
        __syncthreads();
    }
    // ---- L5: 256 -> 256 ----
    {
        float acc[4];
        #pragma unroll
        for (int p = 0; p < 4; ++p) acc[p] = 0.f;
        const int c0 = lane * 4;
        const int kb = q * 16;
        #pragma unroll 8
        for (int k = kb; k < kb + 16; ++k) {
            const float s = bufA[k];
            float fv[4]; unpack4(*(const uint2*)(Wp2 + (size_t)k * 256 + c0), fv);
            #pragma unroll
            for (int p = 0; p < 4; ++p) acc[p] += s * fv[p];
        }
        #pragma unroll
        for (int p = 0; p < 4; ++p) part[q][c0 + p] = acc[p];
        __syncthreads();
        if (t < 256) {
            float a = bf2f(bp2[t]);
            #pragma unroll
            for (int p = 0; p < 16; ++p) a += part[p][t];
            bufB[t] = elu_fast(a);
        }
        __syncthreads();
    }
    // ---- L6: 256 -> 19 + mask ----
    {
        float a = 0.f;
        const int kb = q * 16;
        if (lane < NACT) {
            #pragma unroll 8
            for (int k = kb; k < kb + 16; ++k)
                a += bufB[k] * bf2f(Wp3[(size_t)k * NACT + lane]);
            part[q][lane] = a;
        }
        __syncthreads();
        if (t < NACT) {
            float v = bf2f(bp3[t]);
            #pragma unroll
            for (int p = 0; p < 16; ++p) v += part[p][t];
            v += amask[b * NACT + t] ? 0.f : NEG_INF_F;
            v = fminf(fmaxf(v, -BF16_SAFE_F), BF16_SAFE_F);
            out[b * NACT + t] = f2bf(v);
        }
    }
}

extern "C" void kernel_launch(void* const* d_in, const int* in_sizes, int n_in,
                              void* d_out, int out_size, void* d_ws, size_t ws_size,
                              hipStream_t stream) {
    const ushort_t* gmap  = (const ushort_t*)d_in[0];
    const int*      pos   = (const int*)     d_in[1];
    const int*      amask = (const int*)     d_in[2];
    const ushort_t* Ws    = (const ushort_t*)d_in[3];
    const ushort_t* Wn    = (const ushort_t*)d_in[4];
    const ushort_t* bs    = (const ushort_t*)d_in[5];
    const ushort_t* Wd1   = (const ushort_t*)d_in[6];
    const ushort_t* bd1   = (const ushort_t*)d_in[7];
    const ushort_t* Wd2   = (const ushort_t*)d_in[8];
    const ushort_t* bd2   = (const ushort_t*)d_in[9];
    const ushort_t* Wd3   = (const ushort_t*)d_in[10];
    const ushort_t* bd3   = (const ushort_t*)d_in[11];
    const ushort_t* Wp1   = (const ushort_t*)d_in[12];
    const ushort_t* bp1   = (const ushort_t*)d_in[13];
    const ushort_t* Wp2   = (const ushort_t*)d_in[14];
    const ushort_t* bp2   = (const ushort_t*)d_in[15];
    const ushort_t* Wp3   = (const ushort_t*)d_in[16];
    const ushort_t* bp3   = (const ushort_t*)d_in[17];

    // Workspace: x1 (33.6 MB) + frags (64 KB) + s0/s1 (128 KB) + stg (320 KB).
    ushort_t* x1 = (ushort_t*)d_ws;
    ushort_t* wfrag = x1 + (size_t)BATCH * NTOT * FD;
    float* s0s1 = (float*)(wfrag + 4096 * 8);
    float* s0 = s0s1;
    float* s1 = s0s1 + BATCH * FD;
    float* stg = s0s1 + 2 * BATCH * FD;

    setup_kernel<<<32, 256, 0, stream>>>(Ws, Wn, wfrag, s0s1);

    gnn_layer1<<<16 * BATCH, 256, 0, stream>>>(gmap, x1, wfrag, bs, s0, s1);

    head_window<<<640, 256, 0, stream>>>(x1, pos, Ws, Wn, bs, s0, s1, stg);

    head_mlp<<<BATCH, 1024, 0, stream>>>(stg, amask,
                                         Wd1, bd1, Wd2, bd2, Wd3, bd3,
                                         Wp1, bp1, Wp2, bp2, Wp3, bp3,
                                         (ushort_t*)d_out);
}

// Round 8
// 188.568 us; speedup vs baseline: 3.4837x; 1.0974x over previous
//
#include <hip/hip_runtime.h>
#include <hip/hip_bf16.h>

#define BATCH 128
#define SGRID 32
#define NCELL 1024
#define NTOT  1025
#define FD    128
#define NACT  19
#define NEG_INF_F  (-3.4028234663852886e38f)  // jnp.finfo(float32).min
#define BF16_SAFE_F (3.3e38f)                 // < bf16 max finite (3.3895e38)
#define XSTR 136                              // LDS row stride (bf16); 272B keeps b128 align

typedef unsigned short ushort_t;
typedef unsigned int   uint_t;
typedef short   short8   __attribute__((ext_vector_type(8)));
typedef float   floatx16 __attribute__((ext_vector_type(16)));

__device__ __forceinline__ float elu_fast(float v) {   // bf16-accurate ELU
    return v > 0.f ? v : (__expf(v) - 1.f);
}
__device__ __forceinline__ float bf2f(ushort_t h) {
    union { uint_t u; float f; } v; v.u = ((uint_t)h) << 16; return v.f;
}
__device__ __forceinline__ ushort_t f2bf(float f) {   // round-to-nearest-even
    union { float f; uint_t u; } v; v.f = f;
    uint_t r = v.u + 0x7FFFu + ((v.u >> 16) & 1u);
    return (ushort_t)(r >> 16);
}
__device__ __forceinline__ uint_t pkbf(float a, float b) {  // v_cvt_pk_bf16_f32
    union { __hip_bfloat162 h; uint_t u; } v;
    v.h = __float22bfloat162_rn(make_float2(a, b));
    return v.u;
}
__device__ __forceinline__ void unpack2(uint_t u, float& a, float& b) {
    union { uint_t x; float f; } lo, hi;
    lo.x = u << 16; hi.x = u & 0xFFFF0000u;
    a = lo.f; b = hi.f;
}
__device__ __forceinline__ void unpack8(uint4 v, float* f) {
    unpack2(v.x, f[0], f[1]); unpack2(v.y, f[2], f[3]);
    unpack2(v.z, f[4], f[5]); unpack2(v.w, f[6], f[7]);
}
__device__ __forceinline__ void unpack4(uint2 v, float* f) {
    unpack2(v.x, f[0], f[1]); unpack2(v.y, f[2], f[3]);
}

// ---------------------------------------------------------------------------
// Setup: pack LAYER-1 MFMA B-fragments (4096 groups) + zero s0/s1 sum buffers.
// ---------------------------------------------------------------------------
__global__ __launch_bounds__(256) void setup_kernel(
    const ushort_t* __restrict__ Ws,   // 3 x 128 x 128, k-major (layer 0 used)
    const ushort_t* __restrict__ Wn,
    ushort_t* __restrict__ wfrag,
    float* __restrict__ s0s1)
{
    const int g = blockIdx.x * 256 + threadIdx.x;   // 8192 threads
    if (g < 4096) {
        const int lane = g & 63;
        const int ks   = (g >> 6) & 7;
        const int nt   = (g >> 9) & 3;
        const int p    = (g >> 11) & 1;
        const ushort_t* W = p ? Wn : Ws;            // layer 0
        const int k0  = ks * 16 + (lane >> 5) * 8;
        const int col = nt * 32 + (lane & 31);
        ushort_t v[8];
        #pragma unroll
        for (int j = 0; j < 8; ++j) v[j] = W[(size_t)(k0 + j) * FD + col];
        uint4 u;
        u.x = v[0] | ((uint_t)v[1] << 16); u.y = v[2] | ((uint_t)v[3] << 16);
        u.z = v[4] | ((uint_t)v[5] << 16); u.w = v[6] | ((uint_t)v[7] << 16);
        *(uint4*)(wfrag + (size_t)g * 8) = u;
    } else {
        const int idx = g - 4096;                   // 4096 threads x 8 floats
        float4 z = make_float4(0.f, 0.f, 0.f, 0.f);
        *(float4*)(s0s1 + (size_t)idx * 8)     = z;
        *(float4*)(s0s1 + (size_t)idx * 8 + 4) = z;
    }
}

// ---------------------------------------------------------------------------
// GNN layer 1 (full grid) — proven row-pair structure + atomic s0/s1 sums.
// ---------------------------------------------------------------------------
__global__ __launch_bounds__(256, 4) void gnn_layer1(
    const ushort_t* __restrict__ xprev,   // gmap, B x 1024 x 128
    ushort_t* __restrict__ xnext,         // x1,   B x 1025 x 128 (meta row unused)
    const ushort_t* __restrict__ wfrag_layer,
    const ushort_t* __restrict__ bs,
    float* __restrict__ s0,
    float* __restrict__ s1)
{
    const int i = blockIdx.x;
    const int xcd = i & 7;
    const int j = i >> 3;                  // 0..255
    const int b = xcd * 16 + (j >> 4);
    const int rb = j & 15;
    const int t = threadIdx.x;
    const ushort_t* xb = xprev + (size_t)b * (NCELL * FD);
    ushort_t* yb = xnext + (size_t)b * (NTOT * FD);

    __shared__ alignas(16) ushort_t xt[64 * XSTR];   // x tile / out tile
    __shared__ alignas(16) ushort_t at[64 * XSTR];   // agg tile / f32 scratch

    const int r0 = rb * 2;

    const ushort_t* src = xb + (size_t)(r0 * SGRID) * FD;
    uint4 mainT[4], haloT[4];
    const uint4 zero4 = make_uint4(0u, 0u, 0u, 0u);
    #pragma unroll
    for (int jj = 0; jj < 4; ++jj) {
        const int e8 = (t + 256 * jj) * 8;     // 0..8184
        const int cc = e8 >> 7, k = e8 & 127;
        const int rr = cc >> 5, c = cc & 31;
        mainT[jj] = *(const uint4*)(src + e8);
        const int grow = (rr == 0) ? (r0 - 1) : (r0 + 2);
        haloT[jj] = (grow >= 0 && grow < SGRID)
            ? *(const uint4*)(xb + (size_t)(grow * SGRID + c) * FD + k) : zero4;
    }
    #pragma unroll
    for (int jj = 0; jj < 4; ++jj) {
        const int e8 = (t + 256 * jj) * 8;
        const int cc = e8 >> 7, k = e8 & 127;
        *(uint4*)&xt[cc * XSTR + k] = mainT[jj];
    }
    // s0 partials from mainT.
    {
        float sp[8];
        #pragma unroll
        for (int q = 0; q < 8; ++q) sp[q] = 0.f;
        #pragma unroll
        for (int jj = 0; jj < 4; ++jj) {
            float f[8]; unpack8(mainT[jj], f);
            #pragma unroll
            for (int q = 0; q < 8; ++q) sp[q] += f[q];
        }
        float* atF = (float*)at;               // [16][128] f32 scratch
        const int base = (t >> 4) * 128 + (t & 15) * 8;
        #pragma unroll
        for (int q = 0; q < 8; ++q) atF[base + q] = sp[q];
    }
    __syncthreads();
    if (t < 128) {
        const float* atF = (const float*)at;
        float s = 0.f;
        #pragma unroll
        for (int gI = 0; gI < 16; ++gI) s += atF[gI * 128 + t];
        atomicAdd(&s0[b * 128 + t], s);
    }
    __syncthreads();   // atF reads done -> agg phase may overwrite at

    // Build agg tile (bf16).
    #pragma unroll
    for (int jj = 0; jj < 4; ++jj) {
        const int e8 = (t + 256 * jj) * 8;
        const int cc = e8 >> 7, k = e8 & 127;
        const int c = cc & 31;
        float s[8];
        unpack8(*(const uint4*)&xt[(cc ^ 32) * XSTR + k], s);   // inner vertical
        if (c > 0) {
            float f[8]; unpack8(*(const uint4*)&xt[(cc - 1) * XSTR + k], f);
            #pragma unroll
            for (int q = 0; q < 8; ++q) s[q] += f[q];
        }
        if (c < 31) {
            float f[8]; unpack8(*(const uint4*)&xt[(cc + 1) * XSTR + k], f);
            #pragma unroll
            for (int q = 0; q < 8; ++q) s[q] += f[q];
        }
        {
            float f[8]; unpack8(haloT[jj], f);
            #pragma unroll
            for (int q = 0; q < 8; ++q) s[q] += f[q];
        }
        uint4 u;
        u.x = pkbf(s[0], s[1]); u.y = pkbf(s[2], s[3]);
        u.z = pkbf(s[4], s[5]); u.w = pkbf(s[6], s[7]);
        *(uint4*)&at[cc * XSTR + k] = u;
    }
    __syncthreads();

    // MFMA GEMM: M=64 x N=128 x K=256.
    const int w = t >> 6;
    const int l = t & 63;
    const int m0 = l & 31;
    const int koff = (l >> 5) * 8;

    floatx16 acc0, acc1;
    #pragma unroll
    for (int q = 0; q < 16; ++q) { acc0[q] = 0.f; acc1[q] = 0.f; }

    #pragma unroll
    for (int p = 0; p < 2; ++p) {
        const ushort_t* X = p ? at : xt;
        const ushort_t* WF = wfrag_layer + (size_t)((p * 4 + w) * 8) * 64 * 8;
        #pragma unroll
        for (int ks = 0; ks < 8; ++ks) {
            const short8 bfrag = *(const short8*)(WF + (size_t)(ks * 64 + l) * 8);
            const short8 a0 = *(const short8*)&X[m0 * XSTR + ks * 16 + koff];
            const short8 a1 = *(const short8*)&X[(m0 + 32) * XSTR + ks * 16 + koff];
            acc0 = __builtin_amdgcn_mfma_f32_32x32x16_bf16(a0, bfrag, acc0, 0, 0, 0);
            acc1 = __builtin_amdgcn_mfma_f32_32x32x16_bf16(a1, bfrag, acc1, 0, 0, 0);
        }
    }
    __syncthreads();

    // Epilogue: bias + elu -> LDS out tile; per-col f32 sums -> at scratch.
    const int col = w * 32 + (l & 31);
    const float bias = bf2f(bs[col]);
    float colsum = 0.f;
    #pragma unroll
    for (int mt = 0; mt < 2; ++mt) {
        const floatx16 A = mt ? acc1 : acc0;
        #pragma unroll
        for (int r = 0; r < 16; ++r) {
            const int rowC = (r & 3) + 8 * (r >> 2) + 4 * (l >> 5);
            const float v = elu_fast(A[r] + bias);
            colsum += v;
            xt[(mt * 32 + rowC) * XSTR + col] = f2bf(v);
        }
    }
    ((float*)at)[col * 2 + (l >> 5)] = colsum;
    __syncthreads();
    if (t < 128) {
        const float* atF = (const float*)at;
        atomicAdd(&s1[b * 128 + t], atF[t * 2] + atF[t * 2 + 1]);
    }
    ushort_t* dst = yb + (size_t)(r0 * SGRID) * FD;
    #pragma unroll
    for (int jj = 0; jj < 4; ++jj) {
        const int e8 = (t + 256 * jj) * 8;
        const int cc = e8 >> 7, k = e8 & 127;
        *(uint4*)(dst + e8) = *(const uint4*)&xt[cc * XSTR + k];
    }
}

// ---------------------------------------------------------------------------
// Head windows v2: 640 blocks x 512 threads. Vectorized matvecs:
// thread = (cg: 4 output cols, kg: 16-way K-split of 8 k). All weight loads
// uint2 (4 bf16); all 5 x2 cells share one K-pass (acc[5][4] in regs).
// Compile-time neighbor tables. LDS ~23 KB.
// ---------------------------------------------------------------------------
__global__ __launch_bounds__(512) void head_window(
    const ushort_t* __restrict__ x1g,     // bf16, B x 1025 x 128
    const int* __restrict__ pos,
    const ushort_t* __restrict__ Ws,      // 3 x 128 x 128
    const ushort_t* __restrict__ Wn,
    const ushort_t* __restrict__ bs,      // 3 x 128
    const float* __restrict__ s0,
    const float* __restrict__ s1,
    float* __restrict__ stg)              // f32, B x 640
{
    const int xcd = blockIdx.x & 7;
    const int idx = blockIdx.x >> 3;       // 0..79
    const int b = xcd * 16 + idx / 5;
    const int g = idx % 5;
    const int t = threadIdx.x;
    const int f = t & 127;
    const int cg = t & 31;                 // col group: cols [cg*4, cg*4+4)
    const int c0 = cg * 4;
    const int kg = t >> 5;                 // 0..15, k range [kg*8, kg*8+8)
    const int k0 = kg * 8;

    // Diamond |dr|+|dc|<=2 around the plus cell P (13 cells).
    // idx:   0    1    2    3    4    5    6    7    8    9   10   11   12
    // off: (-2,0)(-1,-1)(-1,0)(-1,1)(0,-2)(0,-1)(0,0)(0,1)(0,2)(1,-1)(1,0)(1,1)(2,0)
    __shared__ float x1d[13][128];         // 6.5 KB
    __shared__ float x2d[5][128];
    __shared__ float aggd[5][128];
    __shared__ float m1[128], m2[128], agg3[128];
    __shared__ float s0L[128], s1L[128];
    __shared__ float part[16][128];        // 8 KB

    const int OFFR[5] = {-1, 0, 1, 0, 0};
    const int OFFC[5] = {0, -1, 0, 1, 0};
    const int pr = pos[b * 2 + 0] + OFFR[g];
    const int pc = pos[b * 2 + 1] + OFFC[g];

    const ushort_t* Wn1 = Wn;
    const ushort_t* Ws2 = Ws + FD * FD;
    const ushort_t* Wn2 = Wn + FD * FD;
    const ushort_t* Ws3 = Ws + 2 * FD * FD;
    const ushort_t* Wn3 = Wn + 2 * FD * FD;

    // ---- Phase 1: stage s0/s1; load x1 diamond (uint4, zero out-of-grid) ---
    if (t < 128)      s0L[t] = s0[b * 128 + t];
    else if (t < 256) s1L[t - 128] = s1[b * 128 + (t - 128)];
    {
        const int D13R[13] = {-2,-1,-1,-1, 0, 0, 0, 0, 0, 1, 1, 1, 2};
        const int D13C[13] = { 0,-1, 0, 1,-2,-1, 0, 1, 2,-1, 0, 1, 0};
        if (t < 208) {                      // 13 cells x 16 uint4 groups
            const int ci = t >> 4, kq = (t & 15) * 8;
            const int r = pr + D13R[ci], c = pc + D13C[ci];
            float fv[8];
            if (r >= 0 && r < SGRID && c >= 0 && c < SGRID) {
                unpack8(*(const uint4*)(x1g + ((size_t)b * NTOT + r * SGRID + c) * FD + kq), fv);
            } else {
                #pragma unroll
                for (int jq = 0; jq < 8; ++jq) fv[jq] = 0.f;
            }
            #pragma unroll
            for (int jq = 0; jq < 8; ++jq) x1d[ci][kq + jq] = fv[jq];
        }
    }
    __syncthreads();

    // ---- Phase 2: m1 = elu(b1 + s0 @ Wn1), 16-way K-split ----
    {
        float acc[4] = {0.f, 0.f, 0.f, 0.f};
        #pragma unroll
        for (int i = 0; i < 8; ++i) {
            const int k = k0 + i;
            float wv[4]; unpack4(*(const uint2*)(Wn1 + k * FD + c0), wv);
            const float sv = s0L[k];
            #pragma unroll
            for (int jq = 0; jq < 4; ++jq) acc[jq] += sv * wv[jq];
        }
        #pragma unroll
        for (int jq = 0; jq < 4; ++jq) part[kg][c0 + jq] = acc[jq];
    }
    __syncthreads();
    if (t < 128) {
        float a = bf2f(bs[f]);
        #pragma unroll
        for (int p = 0; p < 16; ++p) a += part[p][f];
        m1[f] = elu_fast(a);
    }
    __syncthreads();

    // ---- Phase 3: m2 = elu(b2 + m1 @ Ws2 + s1 @ Wn2) ----
    {
        float acc[4] = {0.f, 0.f, 0.f, 0.f};
        #pragma unroll
        for (int i = 0; i < 8; ++i) {
            const int k = k0 + i;
            float wsv[4], wnv[4];
            unpack4(*(const uint2*)(Ws2 + k * FD + c0), wsv);
            unpack4(*(const uint2*)(Wn2 + k * FD + c0), wnv);
            const float mv = m1[k], sv = s1L[k];
            #pragma unroll
            for (int jq = 0; jq < 4; ++jq) acc[jq] += mv * wsv[jq] + sv * wnv[jq];
        }
        #pragma unroll
        for (int jq = 0; jq < 4; ++jq) part[kg][c0 + jq] = acc[jq];
    }
    __syncthreads();
    if (t < 128) {
        float a = bf2f(bs[FD + f]);
        #pragma unroll
        for (int p = 0; p < 16; ++p) a += part[p][f];
        m2[f] = elu_fast(a);
    }
    // ---- Phase 4a: agg for 5 x2 cells (compile-time neighbor table) ----
    // C5 diamond idx: cell0=(-1,0)->2, cell1=(0,-1)->5, cell2=(0,0)->6,
    //                 cell3=(0,1)->7, cell4=(1,0)->10.
    // NB[cc] = D13 idx of 4-neighbors; zero-padded x1d masks the grid edge.
    if (t < 128) {
        const float mm = m1[t];   // m1 ready (barrier before phase 3 finalize)
        aggd[0][t] = x1d[0][t]  + x1d[6][t]  + x1d[1][t] + x1d[3][t]  + mm;
        aggd[1][t] = x1d[1][t]  + x1d[9][t]  + x1d[4][t] + x1d[6][t]  + mm;
        aggd[2][t] = x1d[2][t]  + x1d[10][t] + x1d[5][t] + x1d[7][t]  + mm;
        aggd[3][t] = x1d[3][t]  + x1d[11][t] + x1d[6][t] + x1d[8][t]  + mm;
        aggd[4][t] = x1d[6][t]  + x1d[12][t] + x1d[9][t] + x1d[11][t] + mm;
    }
    __syncthreads();

    // ---- Phase 4b: x2 at 5 cells, one shared K-pass (acc[5][4]) ----
    {
        float acc[5][4];
        #pragma unroll
        for (int cc = 0; cc < 5; ++cc)
            #pragma unroll
            for (int jq = 0; jq < 4; ++jq) acc[cc][jq] = 0.f;
        #pragma unroll
        for (int i = 0; i < 8; ++i) {
            const int k = k0 + i;
            float wsv[4], wnv[4];
            unpack4(*(const uint2*)(Ws2 + k * FD + c0), wsv);
            unpack4(*(const uint2*)(Wn2 + k * FD + c0), wnv);
            const float xv0 = x1d[2][k],  av0 = aggd[0][k];
            const float xv1 = x1d[5][k],  av1 = aggd[1][k];
            const float xv2 = x1d[6][k],  av2 = aggd[2][k];
            const float xv3 = x1d[7][k],  av3 = aggd[3][k];
            const float xv4 = x1d[10][k], av4 = aggd[4][k];
            #pragma unroll
            for (int jq = 0; jq < 4; ++jq) {
                acc[0][jq] += xv0 * wsv[jq] + av0 * wnv[jq];
                acc[1][jq] += xv1 * wsv[jq] + av1 * wnv[jq];
                acc[2][jq] += xv2 * wsv[jq] + av2 * wnv[jq];
                acc[3][jq] += xv3 * wsv[jq] + av3 * wnv[jq];
                acc[4][jq] += xv4 * wsv[jq] + av4 * wnv[jq];
            }
        }
        #pragma unroll
        for (int cc = 0; cc < 5; ++cc) {
            #pragma unroll
            for (int jq = 0; jq < 4; ++jq) part[kg][c0 + jq] = acc[cc][jq];
            __syncthreads();
            if (t < 128) {
                float a = bf2f(bs[FD + f]);
                #pragma unroll
                for (int p = 0; p < 16; ++p) a += part[p][f];
                x2d[cc][f] = elu_fast(a);
            }
            __syncthreads();
        }
    }

    // ---- Phase 5a: agg3 at P (mask out-of-grid neighbors) ----
    if (t < 128) {
        float a = m2[t];
        if (pr - 1 >= 0)    a += x2d[0][t];    // (-1,0)
        if (pr + 1 < SGRID) a += x2d[4][t];    // (1,0)
        if (pc - 1 >= 0)    a += x2d[1][t];    // (0,-1)
        if (pc + 1 < SGRID) a += x2d[3][t];    // (0,1)
        agg3[t] = a;
    }
    __syncthreads();

    // ---- Phase 5b: x3 at P; write st slice ----
    {
        float acc[4] = {0.f, 0.f, 0.f, 0.f};
        #pragma unroll
        for (int i = 0; i < 8; ++i) {
            const int k = k0 + i;
            float wsv[4], wnv[4];
            unpack4(*(const uint2*)(Ws3 + k * FD + c0), wsv);
            unpack4(*(const uint2*)(Wn3 + k * FD + c0), wnv);
            const float xv = x2d[2][k], av = agg3[k];
            #pragma unroll
            for (int jq = 0; jq < 4; ++jq) acc[jq] += xv * wsv[jq] + av * wnv[jq];
        }
        #pragma unroll
        for (int jq = 0; jq < 4; ++jq) part[kg][c0 + jq] = acc[jq];
    }
    __syncthreads();
    if (t < 128) {
        const bool ig = (pr >= 0 && pr < SGRID && pc >= 0 && pc < SGRID);
        float a = bf2f(bs[2 * FD + f]);
        #pragma unroll
        for (int p = 0; p < 16; ++p) a += part[p][f];
        stg[(size_t)b * 640 + g * 128 + f] = ig ? elu_fast(a) : 0.f;
    }
}

// ---------------------------------------------------------------------------
// Head MLP: proven 16-wave structure; st comes from workspace.
// 128 blocks (XCD-swizzled, 1 batch each) x 1024 threads.
// ---------------------------------------------------------------------------
__global__ __launch_bounds__(1024) void head_mlp(
    const float* __restrict__ stg,        // f32, B x 640
    const int* __restrict__ amask,
    const ushort_t* __restrict__ Wd1, const ushort_t* __restrict__ bd1,
    const ushort_t* __restrict__ Wd2, const ushort_t* __restrict__ bd2,
    const ushort_t* __restrict__ Wd3, const ushort_t* __restrict__ bd3,
    const ushort_t* __restrict__ Wp1, const ushort_t* __restrict__ bp1,
    const ushort_t* __restrict__ Wp2, const ushort_t* __restrict__ bp2,
    const ushort_t* __restrict__ Wp3, const ushort_t* __restrict__ bp3,
    ushort_t* __restrict__ out)           // bf16, B x 19
{
    const int t = threadIdx.x;
    const int b = (blockIdx.x & 7) * 16 + (blockIdx.x >> 3);
    const int q = t >> 6;             // wave 0..15
    const int lane = t & 63;

    __shared__ float st[640];
    __shared__ float bufA[512];
    __shared__ float bufB[512];
    __shared__ float part[16][512];

    if (t < 640) st[t] = stg[(size_t)b * 640 + t];
    __syncthreads();

    // ---- L1: 640 -> 512 ----
    {
        float acc[8];
        #pragma unroll
        for (int p = 0; p < 8; ++p) acc[p] = 0.f;
        const int c0 = lane * 8;
        const int kb = q * 40;
        #pragma unroll 8
        for (int k = kb; k < kb + 40; ++k) {
            const float s = st[k];
            float fv[8]; unpack8(*(const uint4*)(Wd1 + (size_t)k * 512 + c0), fv);
            #pragma unroll
            for (int p = 0; p < 8; ++p) acc[p] += s * fv[p];
        }
        #pragma unroll
        for (int p = 0; p < 8; ++p) part[q][c0 + p] = acc[p];
        __syncthreads();
        if (t < 512) {
            float a = bf2f(bd1[t]);
            #pragma unroll
            for (int p = 0; p < 16; ++p) a += part[p][t];
            bufA[t] = elu_fast(a);
        }
        __syncthreads();
    }
    // ---- L2: 512 -> 512 ----
    {
        float acc[8];
        #pragma unroll
        for (int p = 0; p < 8; ++p) acc[p] = 0.f;
        const int c0 = lane * 8;
        const int kb = q * 32;
        #pragma unroll 8
        for (int k = kb; k < kb + 32; ++k) {
            const float s = bufA[k];
            float fv[8]; unpack8(*(const uint4*)(Wd2 + (size_t)k * 512 + c0), fv);
            #pragma unroll
            for (int p = 0; p < 8; ++p) acc[p] += s * fv[p];
        }
        #pragma unroll
        for (int p = 0; p < 8; ++p) part[q][c0 + p] = acc[p];
        __syncthreads();
        if (t < 512) {
            float a = bf2f(bd2[t]);
            #pragma unroll
            for (int p = 0; p < 16; ++p) a += part[p][t];
            bufB[t] = elu_fast(a);
        }
        __syncthreads();
    }
    // ---- L3: 512 -> 256 ----
    {
        float acc[4];
        #pragma unroll
        for (int p = 0; p < 4; ++p) acc[p] = 0.f;
        const int c0 = lane * 4;
        const int kb = q * 32;
        #pragma unroll 8
        for (int k = kb; k < kb + 32; ++k) {
            const float s = bufB[k];
            float fv[4]; unpack4(*(const uint2*)(Wd3 + (size_t)k * 256 + c0), fv);
            #pragma unroll
            for (int p = 0; p < 4; ++p) acc[p] += s * fv[p];
        }
        #pragma unroll
        for (int p = 0; p < 4; ++p) part[q][c0 + p] = acc[p];
        __syncthreads();
        if (t < 256) {
            float a = bf2f(bd3[t]);
            #pragma unroll
            for (int p = 0; p < 16; ++p) a += part[p][t];
            st[t] = elu_fast(a);
        }
        __syncthreads();
    }
    // ---- L4: 256 -> 256 ----
    {
        float acc[4];
        #pragma unroll
        for (int p = 0; p < 4; ++p) acc[p] = 0.f;
        const int c0 = lane * 4;
        const int kb = q * 16;
        #pragma unroll 8
        for (int k = kb; k < kb + 16; ++k) {
            const float s = st[k];
            float fv[4]; unpack4(*(const uint2*)(Wp1 + (size_t)k * 256 + c0), fv);
            #pragma unroll
            for (int p = 0; p < 4; ++p) acc[p] += s * fv[p];
        }
        #pragma unroll
        for (int p = 0; p < 4; ++p) part[q][c0 + p] = acc[p];
        __syncthreads();
        if (t < 256) {
            float a = bf2f(bp1[t]);
            #pragma unroll
            for (int p = 0; p < 16; ++p) a += part[p][t];
            bufA[t] = elu_fast(a);
        }
        __syncthreads();
    }
    // ---- L5: 256 -> 256 ----
    {
        float acc[4];
        #pragma unroll
        for (int p = 0; p < 4; ++p) acc[p] = 0.f;
        const int c0 = lane * 4;
        const int kb = q * 16;
        #pragma unroll 8
        for (int k = kb; k < kb + 16; ++k) {
            const float s = bufA[k];
            float fv[4]; unpack4(*(const uint2*)(Wp2 + (size_t)k * 256 + c0), fv);
            #pragma unroll
            for (int p = 0; p < 4; ++p) acc[p] += s * fv[p];
        }
        #pragma unroll
        for (int p = 0; p < 4; ++p) part[q][c0 + p] = acc[p];
        __syncthreads();
        if (t < 256) {
            float a = bf2f(bp2[t]);
            #pragma unroll
            for (int p = 0; p < 16; ++p) a += part[p][t];
            bufB[t] = elu_fast(a);
        }
        __syncthreads();
    }
    // ---- L6: 256 -> 19 + mask ----
    {
        float a = 0.f;
        const int kb = q * 16;
        if (lane < NACT) {
            #pragma unroll 8
            for (int k = kb; k < kb + 16; ++k)
                a += bufB[k] * bf2f(Wp3[(size_t)k * NACT + lane]);
            part[q][lane] = a;
        }
        __syncthreads();
        if (t < NACT) {
            float v = bf2f(bp3[t]);
            #pragma unroll
            for (int p = 0; p < 16; ++p) v += part[p][t];
            v += amask[b * NACT + t] ? 0.f : NEG_INF_F;
            v = fminf(fmaxf(v, -BF16_SAFE_F), BF16_SAFE_F);
            out[b * NACT + t] = f2bf(v);
        }
    }
}

extern "C" void kernel_launch(void* const* d_in, const int* in_sizes, int n_in,
                              void* d_out, int out_size, void* d_ws, size_t ws_size,
                              hipStream_t stream) {
    const ushort_t* gmap  = (const ushort_t*)d_in[0];
    const int*      pos   = (const int*)     d_in[1];
    const int*      amask = (const int*)     d_in[2];
    const ushort_t* Ws    = (const ushort_t*)d_in[3];
    const ushort_t* Wn    = (const ushort_t*)d_in[4];
    const ushort_t* bs    = (const ushort_t*)d_in[5];
    const ushort_t* Wd1   = (const ushort_t*)d_in[6];
    const ushort_t* bd1   = (const ushort_t*)d_in[7];
    const ushort_t* Wd2   = (const ushort_t*)d_in[8];
    const ushort_t* bd2   = (const ushort_t*)d_in[9];
    const ushort_t* Wd3   = (const ushort_t*)d_in[10];
    const ushort_t* bd3   = (const ushort_t*)d_in[11];
    const ushort_t* Wp1   = (const ushort_t*)d_in[12];
    const ushort_t* bp1   = (const ushort_t*)d_in[13];
    const ushort_t* Wp2   = (const ushort_t*)d_in[14];
    const ushort_t* bp2   = (const ushort_t*)d_in[15];
    const ushort_t* Wp3   = (const ushort_t*)d_in[16];
    const ushort_t* bp3   = (const ushort_t*)d_in[17];

    // Workspace: x1 (33.6 MB) + frags (64 KB) + s0/s1 (128 KB) + stg (320 KB).
    ushort_t* x1 = (ushort_t*)d_ws;
    ushort_t* wfrag = x1 + (size_t)BATCH * NTOT * FD;
    float* s0s1 = (float*)(wfrag + 4096 * 8);
    float* s0 = s0s1;
    float* s1 = s0s1 + BATCH * FD;
    float* stg = s0s1 + 2 * BATCH * FD;

    setup_kernel<<<32, 256, 0, stream>>>(Ws, Wn, wfrag, s0s1);

    gnn_layer1<<<16 * BATCH, 256, 0, stream>>>(gmap, x1, wfrag, bs, s0, s1);

    head_window<<<640, 512, 0, stream>>>(x1, pos, Ws, Wn, bs, s0, s1, stg);

    head_mlp<<<BATCH, 1024, 0, stream>>>(stg, amask,
                                         Wd1, bd1, Wd2, bd2, Wd3, bd3,
                                         Wp1, bp1, Wp2, bp2, Wp3, bp3,
                                         (ushort_t*)d_out);
}

// Round 10
// 183.062 us; speedup vs baseline: 3.5885x; 1.0301x over previous
//
#include <hip/hip_runtime.h>
#include <hip/hip_bf16.h>

#define BATCH 128
#define SGRID 32
#define NCELL 1024
#define NTOT  1025
#define FD    128
#define NACT  19
#define NEG_INF_F  (-3.4028234663852886e38f)  // jnp.finfo(float32).min
#define BF16_SAFE_F (3.3e38f)                 // < bf16 max finite (3.3895e38)
#define XSTR 136                              // LDS row stride (bf16); 272B keeps b128 align

typedef unsigned short ushort_t;
typedef unsigned int   uint_t;
typedef short   short8   __attribute__((ext_vector_type(8)));
typedef float   floatx16 __attribute__((ext_vector_type(16)));

__device__ __forceinline__ float elu_fast(float v) {   // bf16-accurate ELU
    return v > 0.f ? v : (__expf(v) - 1.f);
}
__device__ __forceinline__ float bf2f(ushort_t h) {
    union { uint_t u; float f; } v; v.u = ((uint_t)h) << 16; return v.f;
}
__device__ __forceinline__ ushort_t f2bf(float f) {   // round-to-nearest-even
    union { float f; uint_t u; } v; v.f = f;
    uint_t r = v.u + 0x7FFFu + ((v.u >> 16) & 1u);
    return (ushort_t)(r >> 16);
}
__device__ __forceinline__ uint_t pkbf(float a, float b) {  // v_cvt_pk_bf16_f32
    union { __hip_bfloat162 h; uint_t u; } v;
    v.h = __float22bfloat162_rn(make_float2(a, b));
    return v.u;
}
__device__ __forceinline__ void unpack2(uint_t u, float& a, float& b) {
    union { uint_t x; float f; } lo, hi;
    lo.x = u << 16; hi.x = u & 0xFFFF0000u;
    a = lo.f; b = hi.f;
}
__device__ __forceinline__ void unpack8(uint4 v, float* f) {
    unpack2(v.x, f[0], f[1]); unpack2(v.y, f[2], f[3]);
    unpack2(v.z, f[4], f[5]); unpack2(v.w, f[6], f[7]);
}
__device__ __forceinline__ void unpack4(uint2 v, float* f) {
    unpack2(v.x, f[0], f[1]); unpack2(v.y, f[2], f[3]);
}

// ---------------------------------------------------------------------------
// Setup: pack LAYER-1 MFMA B-fragments (4096 groups) + zero s0/s1 sum buffers.
// ---------------------------------------------------------------------------
__global__ __launch_bounds__(256) void setup_kernel(
    const ushort_t* __restrict__ Ws,   // 3 x 128 x 128, k-major (layer 0 used)
    const ushort_t* __restrict__ Wn,
    ushort_t* __restrict__ wfrag,
    float* __restrict__ s0s1)
{
    const int g = blockIdx.x * 256 + threadIdx.x;   // 8192 threads
    if (g < 4096) {
        const int lane = g & 63;
        const int ks   = (g >> 6) & 7;
        const int nt   = (g >> 9) & 3;
        const int p    = (g >> 11) & 1;
        const ushort_t* W = p ? Wn : Ws;            // layer 0
        const int k0  = ks * 16 + (lane >> 5) * 8;
        const int col = nt * 32 + (lane & 31);
        ushort_t v[8];
        #pragma unroll
        for (int j = 0; j < 8; ++j) v[j] = W[(size_t)(k0 + j) * FD + col];
        uint4 u;
        u.x = v[0] | ((uint_t)v[1] << 16); u.y = v[2] | ((uint_t)v[3] << 16);
        u.z = v[4] | ((uint_t)v[5] << 16); u.w = v[6] | ((uint_t)v[7] << 16);
        *(uint4*)(wfrag + (size_t)g * 8) = u;
    } else {
        const int idx = g - 4096;                   // 4096 threads x 8 floats
        float4 z = make_float4(0.f, 0.f, 0.f, 0.f);
        *(float4*)(s0s1 + (size_t)idx * 8)     = z;
        *(float4*)(s0s1 + (size_t)idx * 8 + 4) = z;
    }
}

// ---------------------------------------------------------------------------
// GNN layer 1 (full grid) — proven row-pair structure + atomic s0/s1 sums.
// ---------------------------------------------------------------------------
__global__ __launch_bounds__(256, 4) void gnn_layer1(
    const ushort_t* __restrict__ xprev,   // gmap, B x 1024 x 128
    ushort_t* __restrict__ xnext,         // x1,   B x 1025 x 128 (meta row unused)
    const ushort_t* __restrict__ wfrag_layer,
    const ushort_t* __restrict__ bs,
    float* __restrict__ s0,
    float* __restrict__ s1)
{
    const int i = blockIdx.x;
    const int xcd = i & 7;
    const int j = i >> 3;                  // 0..255
    const int b = xcd * 16 + (j >> 4);
    const int rb = j & 15;
    const int t = threadIdx.x;
    const ushort_t* xb = xprev + (size_t)b * (NCELL * FD);
    ushort_t* yb = xnext + (size_t)b * (NTOT * FD);

    __shared__ alignas(16) ushort_t xt[64 * XSTR];   // x tile / out tile
    __shared__ alignas(16) ushort_t at[64 * XSTR];   // agg tile / f32 scratch

    const int r0 = rb * 2;

    const ushort_t* src = xb + (size_t)(r0 * SGRID) * FD;
    uint4 mainT[4], haloT[4];
    const uint4 zero4 = make_uint4(0u, 0u, 0u, 0u);
    #pragma unroll
    for (int jj = 0; jj < 4; ++jj) {
        const int e8 = (t + 256 * jj) * 8;     // 0..8184
        const int cc = e8 >> 7, k = e8 & 127;
        const int rr = cc >> 5, c = cc & 31;
        mainT[jj] = *(const uint4*)(src + e8);
        const int grow = (rr == 0) ? (r0 - 1) : (r0 + 2);
        haloT[jj] = (grow >= 0 && grow < SGRID)
            ? *(const uint4*)(xb + (size_t)(grow * SGRID + c) * FD + k) : zero4;
    }
    #pragma unroll
    for (int jj = 0; jj < 4; ++jj) {
        const int e8 = (t + 256 * jj) * 8;
        const int cc = e8 >> 7, k = e8 & 127;
        *(uint4*)&xt[cc * XSTR + k] = mainT[jj];
    }
    // s0 partials from mainT.
    {
        float sp[8];
        #pragma unroll
        for (int q = 0; q < 8; ++q) sp[q] = 0.f;
        #pragma unroll
        for (int jj = 0; jj < 4; ++jj) {
            float f[8]; unpack8(mainT[jj], f);
            #pragma unroll
            for (int q = 0; q < 8; ++q) sp[q] += f[q];
        }
        float* atF = (float*)at;               // [16][128] f32 scratch
        const int base = (t >> 4) * 128 + (t & 15) * 8;
        #pragma unroll
        for (int q = 0; q < 8; ++q) atF[base + q] = sp[q];
    }
    __syncthreads();
    if (t < 128) {
        const float* atF = (const float*)at;
        float s = 0.f;
        #pragma unroll
        for (int gI = 0; gI < 16; ++gI) s += atF[gI * 128 + t];
        atomicAdd(&s0[b * 128 + t], s);
    }
    __syncthreads();   // atF reads done -> agg phase may overwrite at

    // Build agg tile (bf16).
    #pragma unroll
    for (int jj = 0; jj < 4; ++jj) {
        const int e8 = (t + 256 * jj) * 8;
        const int cc = e8 >> 7, k = e8 & 127;
        const int c = cc & 31;
        float s[8];
        unpack8(*(const uint4*)&xt[(cc ^ 32) * XSTR + k], s);   // inner vertical
        if (c > 0) {
            float f[8]; unpack8(*(const uint4*)&xt[(cc - 1) * XSTR + k], f);
            #pragma unroll
            for (int q = 0; q < 8; ++q) s[q] += f[q];
        }
        if (c < 31) {
            float f[8]; unpack8(*(const uint4*)&xt[(cc + 1) * XSTR + k], f);
            #pragma unroll
            for (int q = 0; q < 8; ++q) s[q] += f[q];
        }
        {
            float f[8]; unpack8(haloT[jj], f);
            #pragma unroll
            for (int q = 0; q < 8; ++q) s[q] += f[q];
        }
        uint4 u;
        u.x = pkbf(s[0], s[1]); u.y = pkbf(s[2], s[3]);
        u.z = pkbf(s[4], s[5]); u.w = pkbf(s[6], s[7]);
        *(uint4*)&at[cc * XSTR + k] = u;
    }
    __syncthreads();

    // MFMA GEMM: M=64 x N=128 x K=256.
    const int w = t >> 6;
    const int l = t & 63;
    const int m0 = l & 31;
    const int koff = (l >> 5) * 8;

    floatx16 acc0, acc1;
    #pragma unroll
    for (int q = 0; q < 16; ++q) { acc0[q] = 0.f; acc1[q] = 0.f; }

    #pragma unroll
    for (int p = 0; p < 2; ++p) {
        const ushort_t* X = p ? at : xt;
        const ushort_t* WF = wfrag_layer + (size_t)((p * 4 + w) * 8) * 64 * 8;
        #pragma unroll
        for (int ks = 0; ks < 8; ++ks) {
            const short8 bfrag = *(const short8*)(WF + (size_t)(ks * 64 + l) * 8);
            const short8 a0 = *(const short8*)&X[m0 * XSTR + ks * 16 + koff];
            const short8 a1 = *(const short8*)&X[(m0 + 32) * XSTR + ks * 16 + koff];
            acc0 = __builtin_amdgcn_mfma_f32_32x32x16_bf16(a0, bfrag, acc0, 0, 0, 0);
            acc1 = __builtin_amdgcn_mfma_f32_32x32x16_bf16(a1, bfrag, acc1, 0, 0, 0);
        }
    }
    __syncthreads();

    // Epilogue: bias + elu -> LDS out tile; per-col f32 sums -> at scratch.
    const int col = w * 32 + (l & 31);
    const float bias = bf2f(bs[col]);
    float colsum = 0.f;
    #pragma unroll
    for (int mt = 0; mt < 2; ++mt) {
        const floatx16 A = mt ? acc1 : acc0;
        #pragma unroll
        for (int r = 0; r < 16; ++r) {
            const int rowC = (r & 3) + 8 * (r >> 2) + 4 * (l >> 5);
            const float v = elu_fast(A[r] + bias);
            colsum += v;
            xt[(mt * 32 + rowC) * XSTR + col] = f2bf(v);
        }
    }
    ((float*)at)[col * 2 + (l >> 5)] = colsum;
    __syncthreads();
    if (t < 128) {
        const float* atF = (const float*)at;
        atomicAdd(&s1[b * 128 + t], atF[t * 2] + atF[t * 2 + 1]);
    }
    ushort_t* dst = yb + (size_t)(r0 * SGRID) * FD;
    #pragma unroll
    for (int jj = 0; jj < 4; ++jj) {
        const int e8 = (t + 256 * jj) * 8;
        const int cc = e8 >> 7, k = e8 & 127;
        *(uint4*)(dst + e8) = *(const uint4*)&xt[cc * XSTR + k];
    }
}

// ---------------------------------------------------------------------------
// Meta kernel: per batch, m1 = elu(b1 + s0@Wn1), m2 = elu(b2 + m1@Ws2 + s1@Wn2).
// 128 blocks (XCD-swizzled) x 256 threads; thread = (cg: 4 cols, kg: 8-way
// K-split of 16 k). Removes the serial m1/m2 chain from head_window.
// ---------------------------------------------------------------------------
__global__ __launch_bounds__(256) void meta_kernel(
    const ushort_t* __restrict__ Ws,
    const ushort_t* __restrict__ Wn,
    const ushort_t* __restrict__ bs,
    const float* __restrict__ s0,
    const float* __restrict__ s1,
    float* __restrict__ m1g,             // f32, B x 128
    float* __restrict__ m2g)             // f32, B x 128
{
    const int b = (blockIdx.x & 7) * 16 + (blockIdx.x >> 3);
    const int t = threadIdx.x;
    const int cg = t & 31;
    const int c0 = cg * 4;
    const int kg = t >> 5;               // 0..7
    const int k0 = kg * 16;

    __shared__ float s0L[128], s1L[128], m1L[128];
    __shared__ float part[8][128];

    const ushort_t* Ws2 = Ws + FD * FD;
    const ushort_t* Wn2 = Wn + FD * FD;

    if (t < 128)      s0L[t] = s0[b * 128 + t];
    else              s1L[t - 128] = s1[b * 128 + (t - 128)];
    __syncthreads();

    // m1 partials.
    {
        float acc[4] = {0.f, 0.f, 0.f, 0.f};
        #pragma unroll
        for (int i = 0; i < 16; ++i) {
            const int k = k0 + i;
            float wv[4]; unpack4(*(const uint2*)(Wn + k * FD + c0), wv);
            const float sv = s0L[k];
            #pragma unroll
            for (int jq = 0; jq < 4; ++jq) acc[jq] += sv * wv[jq];
        }
        #pragma unroll
        for (int jq = 0; jq < 4; ++jq) part[kg][c0 + jq] = acc[jq];
    }
    __syncthreads();
    if (t < 128) {
        float a = bf2f(bs[t]);
        #pragma unroll
        for (int p = 0; p < 8; ++p) a += part[p][t];
        const float v = elu_fast(a);
        m1L[t] = v;
        m1g[b * 128 + t] = v;
    }
    __syncthreads();

    // m2 partials.
    {
        float acc[4] = {0.f, 0.f, 0.f, 0.f};
        #pragma unroll
        for (int i = 0; i < 16; ++i) {
            const int k = k0 + i;
            float wsv[4], wnv[4];
            unpack4(*(const uint2*)(Ws2 + k * FD + c0), wsv);
            unpack4(*(const uint2*)(Wn2 + k * FD + c0), wnv);
            const float mv = m1L[k], sv = s1L[k];
            #pragma unroll
            for (int jq = 0; jq < 4; ++jq) acc[jq] += mv * wsv[jq] + sv * wnv[jq];
        }
        #pragma unroll
        for (int jq = 0; jq < 4; ++jq) part[kg][c0 + jq] = acc[jq];
    }
    __syncthreads();
    if (t < 128) {
        float a = bf2f(bs[FD + t]);
        #pragma unroll
        for (int p = 0; p < 8; ++p) a += part[p][t];
        m2g[b * 128 + t] = elu_fast(a);
    }
}

// ---------------------------------------------------------------------------
// Head windows v3: 640 blocks x 512 threads. m1/m2 precomputed (meta_kernel).
// Phase 4b batches all 5 cells' partials into part5[16][640]: 1 barrier +
// 1 wide reduce (was 10 barriers). LDS ~54 KB -> 2 blocks/CU.
// ---------------------------------------------------------------------------
__global__ __launch_bounds__(512) void head_window(
    const ushort_t* __restrict__ x1g,     // bf16, B x 1025 x 128
    const int* __restrict__ pos,
    const ushort_t* __restrict__ Ws,      // 3 x 128 x 128
    const ushort_t* __restrict__ Wn,
    const ushort_t* __restrict__ bs,      // 3 x 128
    const float* __restrict__ m1g,
    const float* __restrict__ m2g,
    float* __restrict__ stg)              // f32, B x 640
{
    const int xcd = blockIdx.x & 7;
    const int idx = blockIdx.x >> 3;       // 0..79
    const int b = xcd * 16 + idx / 5;
    const int g = idx % 5;
    const int t = threadIdx.x;
    const int f = t & 127;
    const int cg = t & 31;                 // col group: cols [cg*4, cg*4+4)
    const int c0 = cg * 4;
    const int kg = t >> 5;                 // 0..15, k range [kg*8, kg*8+8)
    const int k0 = kg * 8;

    // Diamond |dr|+|dc|<=2 around the plus cell P (13 cells).
    // idx:   0    1    2    3    4    5    6    7    8    9   10   11   12
    // off: (-2,0)(-1,-1)(-1,0)(-1,1)(0,-2)(0,-1)(0,0)(0,1)(0,2)(1,-1)(1,0)(1,1)(2,0)
    __shared__ float x1d[13][128];         // 6.5 KB
    __shared__ float x2d[5][128];
    __shared__ float aggd[5][128];
    __shared__ float m1L[128], m2L[128], agg3[128];
    __shared__ float part5[16][640];       // 40 KB

    const int OFFR[5] = {-1, 0, 1, 0, 0};
    const int OFFC[5] = {0, -1, 0, 1, 0};
    const int pr = pos[b * 2 + 0] + OFFR[g];
    const int pc = pos[b * 2 + 1] + OFFC[g];

    const ushort_t* Ws2 = Ws + FD * FD;
    const ushort_t* Wn2 = Wn + FD * FD;
    const ushort_t* Ws3 = Ws + 2 * FD * FD;
    const ushort_t* Wn3 = Wn + 2 * FD * FD;

    // ---- Phase 1: load m1/m2 + x1 diamond (uint4, zero out-of-grid) ----
    if (t < 128)      m1L[t] = m1g[b * 128 + t];
    else if (t < 256) m2L[t - 128] = m2g[b * 128 + (t - 128)];
    {
        const int D13R[13] = {-2,-1,-1,-1, 0, 0, 0, 0, 0, 1, 1, 1, 2};
        const int D13C[13] = { 0,-1, 0, 1,-2,-1, 0, 1, 2,-1, 0, 1, 0};
        if (t < 208) {                      // 13 cells x 16 uint4 groups
            const int ci = t >> 4, kq = (t & 15) * 8;
            const int r = pr + D13R[ci], c = pc + D13C[ci];
            float fv[8];
            if (r >= 0 && r < SGRID && c >= 0 && c < SGRID) {
                unpack8(*(const uint4*)(x1g + ((size_t)b * NTOT + r * SGRID + c) * FD + kq), fv);
            } else {
                #pragma unroll
                for (int jq = 0; jq < 8; ++jq) fv[jq] = 0.f;
            }
            #pragma unroll
            for (int jq = 0; jq < 8; ++jq) x1d[ci][kq + jq] = fv[jq];
        }
    }
    __syncthreads();

    // ---- Phase 4a: agg for 5 x2 cells (compile-time neighbor table) ----
    // C5 diamond idx: cell0=(-1,0)->2, cell1=(0,-1)->5, cell2=(0,0)->6,
    //                 cell3=(0,1)->7, cell4=(1,0)->10. Zero-padded x1d masks edges.
    if (t < 128) {
        const float mm = m1L[t];
        aggd[0][t] = x1d[0][t]  + x1d[6][t]  + x1d[1][t] + x1d[3][t]  + mm;
        aggd[1][t] = x1d[1][t]  + x1d[9][t]  + x1d[4][t] + x1d[6][t]  + mm;
        aggd[2][t] = x1d[2][t]  + x1d[10][t] + x1d[5][t] + x1d[7][t]  + mm;
        aggd[3][t] = x1d[3][t]  + x1d[11][t] + x1d[6][t] + x1d[8][t]  + mm;
        aggd[4][t] = x1d[6][t]  + x1d[12][t] + x1d[9][t] + x1d[11][t] + mm;
    }
    __syncthreads();

    // ---- Phase 4b: x2 at 5 cells, one shared K-pass, batched reduce ----
    {
        float acc[5][4];
        #pragma unroll
        for (int cc = 0; cc < 5; ++cc)
            #pragma unroll
            for (int jq = 0; jq < 4; ++jq) acc[cc][jq] = 0.f;
        #pragma unroll
        for (int i = 0; i < 8; ++i) {
            const int k = k0 + i;
            float wsv[4], wnv[4];
            unpack4(*(const uint2*)(Ws2 + k * FD + c0), wsv);
            unpack4(*(const uint2*)(Wn2 + k * FD + c0), wnv);
            const float xv0 = x1d[2][k],  av0 = aggd[0][k];
            const float xv1 = x1d[5][k],  av1 = aggd[1][k];
            const float xv2 = x1d[6][k],  av2 = aggd[2][k];
            const float xv3 = x1d[7][k],  av3 = aggd[3][k];
            const float xv4 = x1d[10][k], av4 = aggd[4][k];
            #pragma unroll
            for (int jq = 0; jq < 4; ++jq) {
                acc[0][jq] += xv0 * wsv[jq] + av0 * wnv[jq];
                acc[1][jq] += xv1 * wsv[jq] + av1 * wnv[jq];
                acc[2][jq] += xv2 * wsv[jq] + av2 * wnv[jq];
                acc[3][jq] += xv3 * wsv[jq] + av3 * wnv[jq];
                acc[4][jq] += xv4 * wsv[jq] + av4 * wnv[jq];
            }
        }
        #pragma unroll
        for (int cc = 0; cc < 5; ++cc)
            #pragma unroll
            for (int jq = 0; jq < 4; ++jq) part5[kg][cc * 128 + c0 + jq] = acc[cc][jq];
    }
    __syncthreads();
    for (int e = t; e < 640; e += 512) {
        const int cc = e >> 7, ff = e & 127;
        float a = bf2f(bs[FD + ff]);
        #pragma unroll
        for (int p = 0; p < 16; ++p) a += part5[p][e];
        x2d[cc][ff] = elu_fast(a);
    }
    __syncthreads();

    // ---- Phase 5a: agg3 at P (mask out-of-grid neighbors) ----
    if (t < 128) {
        float a = m2L[t];
        if (pr - 1 >= 0)    a += x2d[0][t];    // (-1,0)
        if (pr + 1 < SGRID) a += x2d[4][t];    // (1,0)
        if (pc - 1 >= 0)    a += x2d[1][t];    // (0,-1)
        if (pc + 1 < SGRID) a += x2d[3][t];    // (0,1)
        agg3[t] = a;
    }
    __syncthreads();

    // ---- Phase 5b: x3 at P; write st slice ----
    {
        float acc[4] = {0.f, 0.f, 0.f, 0.f};
        #pragma unroll
        for (int i = 0; i < 8; ++i) {
            const int k = k0 + i;
            float wsv[4], wnv[4];
            unpack4(*(const uint2*)(Ws3 + k * FD + c0), wsv);
            unpack4(*(const uint2*)(Wn3 + k * FD + c0), wnv);
            const float xv = x2d[2][k], av = agg3[k];
            #pragma unroll
            for (int jq = 0; jq < 4; ++jq) acc[jq] += xv * wsv[jq] + av * wnv[jq];
        }
        #pragma unroll
        for (int jq = 0; jq < 4; ++jq) part5[kg][c0 + jq] = acc[jq];
    }
    __syncthreads();
    if (t < 128) {
        const bool ig = (pr >= 0 && pr < SGRID && pc >= 0 && pc < SGRID);
        float a = bf2f(bs[2 * FD + f]);
        #pragma unroll
        for (int p = 0; p < 16; ++p) a += part5[p][f];
        stg[(size_t)b * 640 + g * 128 + f] = ig ? elu_fast(a) : 0.f;
    }
}

// ---------------------------------------------------------------------------
// Head MLP v2: 128 blocks (XCD-swizzled, 1 batch) x 512 threads = 8 waves.
// 8-way K-split, part[8][512]; uint4 weight loads. LDS ~22.5 KB.
// ---------------------------------------------------------------------------
__global__ __launch_bounds__(512) void head_mlp(
    const float* __restrict__ stg,        // f32, B x 640
    const int* __restrict__ amask,
    const ushort_t* __restrict__ Wd1, const ushort_t* __restrict__ bd1,
    const ushort_t* __restrict__ Wd2, const ushort_t* __restrict__ bd2,
    const ushort_t* __restrict__ Wd3, const ushort_t* __restrict__ bd3,
    const ushort_t* __restrict__ Wp1, const ushort_t* __restrict__ bp1,
    const ushort_t* __restrict__ Wp2, const ushort_t* __restrict__ bp2,
    const ushort_t* __restrict__ Wp3, const ushort_t* __restrict__ bp3,
    ushort_t* __restrict__ out)           // bf16, B x 19
{
    const int t = threadIdx.x;
    const int b = (blockIdx.x & 7) * 16 + (blockIdx.x >> 3);
    const int q = t >> 6;             // wave 0..7
    const int lane = t & 63;

    __shared__ float st[640];
    __shared__ float bufA[512];
    __shared__ float bufB[512];
    __shared__ float part[8][512];

    for (int e = t; e < 640; e += 512) st[e] = stg[(size_t)b * 640 + e];
    __syncthreads();

    // ---- L1: 640 -> 512 (80 k per wave; lane owns 8 cols) ----
    {
        float acc[8];
        #pragma unroll
        for (int p = 0; p < 8; ++p) acc[p] = 0.f;
        const int c0 = lane * 8;
        const int kb = q * 80;
        #pragma unroll 8
        for (int k = kb; k < kb + 80; ++k) {
            const float s = st[k];
            float fv[8]; unpack8(*(const uint4*)(Wd1 + (size_t)k * 512 + c0), fv);
            #pragma unroll
            for (int p = 0; p < 8; ++p) acc[p] += s * fv[p];
        }
        #pragma unroll
        for (int p = 0; p < 8; ++p) part[q][c0 + p] = acc[p];
        __syncthreads();
        {
            float a = bf2f(bd1[t]);
            #pragma unroll
            for (int p = 0; p < 8; ++p) a += part[p][t];
            bufA[t] = elu_fast(a);
        }
        __syncthreads();
    }
    // ---- L2: 512 -> 512 (64 k per wave) ----
    {
        float acc[8];
        #pragma unroll
        for (int p = 0; p < 8; ++p) acc[p] = 0.f;
        const int c0 = lane * 8;
        const int kb = q * 64;
        #pragma unroll 8
        for (int k = kb; k < kb + 64; ++k) {
            const float s = bufA[k];
            float fv[8]; unpack8(*(const uint4*)(Wd2 + (size_t)k * 512 + c0), fv);
            #pragma unroll
            for (int p = 0; p < 8; ++p) acc[p] += s * fv[p];
        }
        #pragma unroll
        for (int p = 0; p < 8; ++p) part[q][c0 + p] = acc[p];
        __syncthreads();
        {
            float a = bf2f(bd2[t]);
            #pragma unroll
            for (int p = 0; p < 8; ++p) a += part[p][t];
            bufB[t] = elu_fast(a);
        }
        __syncthreads();
    }
    // ---- L3: 512 -> 256 (64 k per wave; lane owns 4 cols) ----
    {
        float acc[4];
        #pragma unroll
        for (int p = 0; p < 4; ++p) acc[p] = 0.f;
        const int c0 = lane * 4;
        const int kb = q * 64;
        #pragma unroll 8
        for (int k = kb; k < kb + 64; ++k) {
            const float s = bufB[k];
            float fv[4]; unpack4(*(const uint2*)(Wd3 + (size_t)k * 256 + c0), fv);
            #pragma unroll
            for (int p = 0; p < 4; ++p) acc[p] += s * fv[p];
        }
        #pragma unroll
        for (int p = 0; p < 4; ++p) part[q][c0 + p] = acc[p];
        __syncthreads();
        if (t < 256) {
            float a = bf2f(bd3[t]);
            #pragma unroll
            for (int p = 0; p < 8; ++p) a += part[p][t];
            st[t] = elu_fast(a);
        }
        __syncthreads();
    }
    // ---- L4: 256 -> 256 (32 k per wave) ----
    {
        float acc[4];
        #pragma unroll
        for (int p = 0; p < 4; ++p) acc[p] = 0.f;
        const int c0 = lane * 4;
        const int kb = q * 32;
        #pragma unroll 8
        for (int k = kb; k < kb + 32; ++k) {
            const float s = st[k];
            float fv[4]; unpack4(*(const uint2*)(Wp1 + (size_t)k * 256 + c0), fv);
            #pragma unroll
            for (int p = 0; p < 4; ++p) acc[p] += s * fv[p];
        }
        #pragma unroll
        for (int p = 0; p < 4; ++p) part[q][c0 + p] = acc[p];
        __syncthreads();
        if (t < 256) {
            float a = bf2f(bp1[t]);
            #pragma unroll
            for (int p = 0; p < 8; ++p) a += part[p][t];
            bufA[t] = elu_fast(a);
        }
        __syncthreads();
    }
    // ---- L5: 256 -> 256 ----
    {
        float acc[4];
        #pragma unroll
        for (int p = 0; p < 4; ++p) acc[p] = 0.f;
        const int c0 = lane * 4;
        const int kb = q * 32;
        #pragma unroll 8
        for (int k = kb; k < kb + 32; ++k) {
            const float s = bufA[k];
            float fv[4]; unpack4(*(const uint2*)(Wp2 + (size_t)k * 256 + c0), fv);
            #pragma unroll
            for (int p = 0; p < 4; ++p) acc[p] += s * fv[p];
        }
        #pragma unroll
        for (int p = 0; p < 4; ++p) part[q][c0 + p] = acc[p];
        __syncthreads();
        if (t < 256) {
            float a = bf2f(bp2[t]);
            #pragma unroll
            for (int p = 0; p < 8; ++p) a += part[p][t];
            bufB[t] = elu_fast(a);
        }
        __syncthreads();
    }
    // ---- L6: 256 -> 19 + mask ----
    {
        float a = 0.f;
        const int kb = q * 32;
        if (lane < NACT) {
            #pragma unroll 8
            for (int k = kb; k < kb + 32; ++k)
                a += bufB[k] * bf2f(Wp3[(size_t)k * NACT + lane]);
            part[q][lane] = a;
        }
        __syncthreads();
        if (t < NACT) {
            float v = bf2f(bp3[t]);
            #pragma unroll
            for (int p = 0; p < 8; ++p) v += part[p][t];
            v += amask[b * NACT + t] ? 0.f : NEG_INF_F;
            v = fminf(fmaxf(v, -BF16_SAFE_F), BF16_SAFE_F);
            out[b * NACT + t] = f2bf(v);
        }
    }
}

extern "C" void kernel_launch(void* const* d_in, const int* in_sizes, int n_in,
                              void* d_out, int out_size, void* d_ws, size_t ws_size,
                              hipStream_t stream) {
    const ushort_t* gmap  = (const ushort_t*)d_in[0];
    const int*      pos   = (const int*)     d_in[1];
    const int*      amask = (const int*)     d_in[2];
    const ushort_t* Ws    = (const ushort_t*)d_in[3];
    const ushort_t* Wn    = (const ushort_t*)d_in[4];
    const ushort_t* bs    = (const ushort_t*)d_in[5];
    const ushort_t* Wd1   = (const ushort_t*)d_in[6];
    const ushort_t* bd1   = (const ushort_t*)d_in[7];
    const ushort_t* Wd2   = (const ushort_t*)d_in[8];
    const ushort_t* bd2   = (const ushort_t*)d_in[9];
    const ushort_t* Wd3   = (const ushort_t*)d_in[10];
    const ushort_t* bd3   = (const ushort_t*)d_in[11];
    const ushort_t* Wp1   = (const ushort_t*)d_in[12];
    const ushort_t* bp1   = (const ushort_t*)d_in[13];
    const ushort_t* Wp2   = (const ushort_t*)d_in[14];
    const ushort_t* bp2   = (const ushort_t*)d_in[15];
    const ushort_t* Wp3   = (const ushort_t*)d_in[16];
    const ushort_t* bp3   = (const ushort_t*)d_in[17];

    // Workspace: x1 (33.6 MB) + frags + s0/s1 + stg + m1/m2.
    ushort_t* x1 = (ushort_t*)d_ws;
    ushort_t* wfrag = x1 + (size_t)BATCH * NTOT * FD;
    float* s0s1 = (float*)(wfrag + 4096 * 8);
    float* s0 = s0s1;
    float* s1 = s0s1 + BATCH * FD;
    float* stg = s0s1 + 2 * BATCH * FD;
    float* m1g = stg + BATCH * 640;
    float* m2g = m1g + BATCH * FD;

    setup_kernel<<<32, 256, 0, stream>>>(Ws, Wn, wfrag, s0s1);

    gnn_layer1<<<16 * BATCH, 256, 0, stream>>>(gmap, x1, wfrag, bs, s0, s1);

    meta_kernel<<<BATCH, 256, 0, stream>>>(Ws, Wn, bs, s0, s1, m1g, m2g);

    head_window<<<640, 512, 0, stream>>>(x1, pos, Ws, Wn, bs, m1g, m2g, stg);

    head_mlp<<<BATCH, 512, 0, stream>>>(stg, amask,
                                        Wd1, bd1, Wd2, bd2, Wd3, bd3,
                                        Wp1, bp1, Wp2, bp2, Wp3, bp3,
                                        (ushort_t*)d_out);
}

// Round 11
// 181.873 us; speedup vs baseline: 3.6119x; 1.0065x over previous
//
#include <hip/hip_runtime.h>
#include <hip/hip_bf16.h>

#define BATCH 128
#define SGRID 32
#define NCELL 1024
#define NTOT  1025
#define FD    128
#define NACT  19
#define NEG_INF_F  (-3.4028234663852886e38f)  // jnp.finfo(float32).min
#define BF16_SAFE_F (3.3e38f)                 // < bf16 max finite (3.3895e38)
#define XSTR 136                              // LDS row stride (bf16); 272B keeps b128 align

typedef unsigned short ushort_t;
typedef unsigned int   uint_t;
typedef short   short8   __attribute__((ext_vector_type(8)));
typedef float   floatx16 __attribute__((ext_vector_type(16)));

__device__ __forceinline__ float elu_fast(float v) {   // bf16-accurate ELU
    return v > 0.f ? v : (__expf(v) - 1.f);
}
__device__ __forceinline__ float bf2f(ushort_t h) {
    union { uint_t u; float f; } v; v.u = ((uint_t)h) << 16; return v.f;
}
__device__ __forceinline__ ushort_t f2bf(float f) {   // round-to-nearest-even
    union { float f; uint_t u; } v; v.f = f;
    uint_t r = v.u + 0x7FFFu + ((v.u >> 16) & 1u);
    return (ushort_t)(r >> 16);
}
__device__ __forceinline__ uint_t pkbf(float a, float b) {  // v_cvt_pk_bf16_f32
    union { __hip_bfloat162 h; uint_t u; } v;
    v.h = __float22bfloat162_rn(make_float2(a, b));
    return v.u;
}
__device__ __forceinline__ void unpack2(uint_t u, float& a, float& b) {
    union { uint_t x; float f; } lo, hi;
    lo.x = u << 16; hi.x = u & 0xFFFF0000u;
    a = lo.f; b = hi.f;
}
__device__ __forceinline__ void unpack8(uint4 v, float* f) {
    unpack2(v.x, f[0], f[1]); unpack2(v.y, f[2], f[3]);
    unpack2(v.z, f[4], f[5]); unpack2(v.w, f[6], f[7]);
}
__device__ __forceinline__ void unpack4(uint2 v, float* f) {
    unpack2(v.x, f[0], f[1]); unpack2(v.y, f[2], f[3]);
}

// ---------------------------------------------------------------------------
// Setup: pack LAYER-1 MFMA B-fragments (4096 groups) + zero s0/s1 sum buffers.
// ---------------------------------------------------------------------------
__global__ __launch_bounds__(256) void setup_kernel(
    const ushort_t* __restrict__ Ws,   // 3 x 128 x 128, k-major (layer 0 used)
    const ushort_t* __restrict__ Wn,
    ushort_t* __restrict__ wfrag,
    float* __restrict__ s0s1)
{
    const int g = blockIdx.x * 256 + threadIdx.x;   // 8192 threads
    if (g < 4096) {
        const int lane = g & 63;
        const int ks   = (g >> 6) & 7;
        const int nt   = (g >> 9) & 3;
        const int p    = (g >> 11) & 1;
        const ushort_t* W = p ? Wn : Ws;            // layer 0
        const int k0  = ks * 16 + (lane >> 5) * 8;
        const int col = nt * 32 + (lane & 31);
        ushort_t v[8];
        #pragma unroll
        for (int j = 0; j < 8; ++j) v[j] = W[(size_t)(k0 + j) * FD + col];
        uint4 u;
        u.x = v[0] | ((uint_t)v[1] << 16); u.y = v[2] | ((uint_t)v[3] << 16);
        u.z = v[4] | ((uint_t)v[5] << 16); u.w = v[6] | ((uint_t)v[7] << 16);
        *(uint4*)(wfrag + (size_t)g * 8) = u;
    } else {
        const int idx = g - 4096;                   // 4096 threads x 8 floats
        float4 z = make_float4(0.f, 0.f, 0.f, 0.f);
        *(float4*)(s0s1 + (size_t)idx * 8)     = z;
        *(float4*)(s0s1 + (size_t)idx * 8 + 4) = z;
    }
}

// ---------------------------------------------------------------------------
// GNN layer 1 (full grid compute) + atomic s0/s1 sums. x1 is STORED only in
// the 7x7 box around pos[b] (rows pr+-3, cols pc+-3) — the only cells
// head_window ever reads; the other ~97% of writes were dead work.
// ---------------------------------------------------------------------------
__global__ __launch_bounds__(256, 4) void gnn_layer1(
    const ushort_t* __restrict__ xprev,   // gmap, B x 1024 x 128
    ushort_t* __restrict__ xnext,         // x1,   B x 1025 x 128 (box only)
    const ushort_t* __restrict__ wfrag_layer,
    const ushort_t* __restrict__ bs,
    const int* __restrict__ pos,
    float* __restrict__ s0,
    float* __restrict__ s1)
{
    const int i = blockIdx.x;
    const int xcd = i & 7;
    const int j = i >> 3;                  // 0..255
    const int b = xcd * 16 + (j >> 4);
    const int rb = j & 15;
    const int t = threadIdx.x;
    const ushort_t* xb = xprev + (size_t)b * (NCELL * FD);
    ushort_t* yb = xnext + (size_t)b * (NTOT * FD);

    __shared__ alignas(16) ushort_t xt[64 * XSTR];   // x tile / out tile
    __shared__ alignas(16) ushort_t at[64 * XSTR];   // agg tile / f32 scratch

    const int r0 = rb * 2;

    const ushort_t* src = xb + (size_t)(r0 * SGRID) * FD;
    uint4 mainT[4], haloT[4];
    const uint4 zero4 = make_uint4(0u, 0u, 0u, 0u);
    #pragma unroll
    for (int jj = 0; jj < 4; ++jj) {
        const int e8 = (t + 256 * jj) * 8;     // 0..8184
        const int cc = e8 >> 7, k = e8 & 127;
        const int rr = cc >> 5, c = cc & 31;
        mainT[jj] = *(const uint4*)(src + e8);
        const int grow = (rr == 0) ? (r0 - 1) : (r0 + 2);
        haloT[jj] = (grow >= 0 && grow < SGRID)
            ? *(const uint4*)(xb + (size_t)(grow * SGRID + c) * FD + k) : zero4;
    }
    #pragma unroll
    for (int jj = 0; jj < 4; ++jj) {
        const int e8 = (t + 256 * jj) * 8;
        const int cc = e8 >> 7, k = e8 & 127;
        *(uint4*)&xt[cc * XSTR + k] = mainT[jj];
    }
    // s0 partials from mainT.
    {
        float sp[8];
        #pragma unroll
        for (int q = 0; q < 8; ++q) sp[q] = 0.f;
        #pragma unroll
        for (int jj = 0; jj < 4; ++jj) {
            float f[8]; unpack8(mainT[jj], f);
            #pragma unroll
            for (int q = 0; q < 8; ++q) sp[q] += f[q];
        }
        float* atF = (float*)at;               // [16][128] f32 scratch
        const int base = (t >> 4) * 128 + (t & 15) * 8;
        #pragma unroll
        for (int q = 0; q < 8; ++q) atF[base + q] = sp[q];
    }
    __syncthreads();
    if (t < 128) {
        const float* atF = (const float*)at;
        float s = 0.f;
        #pragma unroll
        for (int gI = 0; gI < 16; ++gI) s += atF[gI * 128 + t];
        atomicAdd(&s0[b * 128 + t], s);
    }
    __syncthreads();   // atF reads done -> agg phase may overwrite at

    // Build agg tile (bf16).
    #pragma unroll
    for (int jj = 0; jj < 4; ++jj) {
        const int e8 = (t + 256 * jj) * 8;
        const int cc = e8 >> 7, k = e8 & 127;
        const int c = cc & 31;
        float s[8];
        unpack8(*(const uint4*)&xt[(cc ^ 32) * XSTR + k], s);   // inner vertical
        if (c > 0) {
            float f[8]; unpack8(*(const uint4*)&xt[(cc - 1) * XSTR + k], f);
            #pragma unroll
            for (int q = 0; q < 8; ++q) s[q] += f[q];
        }
        if (c < 31) {
            float f[8]; unpack8(*(const uint4*)&xt[(cc + 1) * XSTR + k], f);
            #pragma unroll
            for (int q = 0; q < 8; ++q) s[q] += f[q];
        }
        {
            float f[8]; unpack8(haloT[jj], f);
            #pragma unroll
            for (int q = 0; q < 8; ++q) s[q] += f[q];
        }
        uint4 u;
        u.x = pkbf(s[0], s[1]); u.y = pkbf(s[2], s[3]);
        u.z = pkbf(s[4], s[5]); u.w = pkbf(s[6], s[7]);
        *(uint4*)&at[cc * XSTR + k] = u;
    }
    __syncthreads();

    // MFMA GEMM: M=64 x N=128 x K=256.
    const int w = t >> 6;
    const int l = t & 63;
    const int m0 = l & 31;
    const int koff = (l >> 5) * 8;

    floatx16 acc0, acc1;
    #pragma unroll
    for (int q = 0; q < 16; ++q) { acc0[q] = 0.f; acc1[q] = 0.f; }

    #pragma unroll
    for (int p = 0; p < 2; ++p) {
        const ushort_t* X = p ? at : xt;
        const ushort_t* WF = wfrag_layer + (size_t)((p * 4 + w) * 8) * 64 * 8;
        #pragma unroll
        for (int ks = 0; ks < 8; ++ks) {
            const short8 bfrag = *(const short8*)(WF + (size_t)(ks * 64 + l) * 8);
            const short8 a0 = *(const short8*)&X[m0 * XSTR + ks * 16 + koff];
            const short8 a1 = *(const short8*)&X[(m0 + 32) * XSTR + ks * 16 + koff];
            acc0 = __builtin_amdgcn_mfma_f32_32x32x16_bf16(a0, bfrag, acc0, 0, 0, 0);
            acc1 = __builtin_amdgcn_mfma_f32_32x32x16_bf16(a1, bfrag, acc1, 0, 0, 0);
        }
    }
    __syncthreads();

    // Epilogue: bias + elu -> LDS out tile; per-col f32 sums -> at scratch.
    const int col = w * 32 + (l & 31);
    const float bias = bf2f(bs[col]);
    float colsum = 0.f;
    #pragma unroll
    for (int mt = 0; mt < 2; ++mt) {
        const floatx16 A = mt ? acc1 : acc0;
        #pragma unroll
        for (int r = 0; r < 16; ++r) {
            const int rowC = (r & 3) + 8 * (r >> 2) + 4 * (l >> 5);
            const float v = elu_fast(A[r] + bias);
            colsum += v;
            xt[(mt * 32 + rowC) * XSTR + col] = f2bf(v);
        }
    }
    ((float*)at)[col * 2 + (l >> 5)] = colsum;
    __syncthreads();
    if (t < 128) {
        const float* atF = (const float*)at;
        atomicAdd(&s1[b * 128 + t], atF[t * 2] + atF[t * 2 + 1]);
    }
    // Guarded store: only the 7x7 box around pos[b] is ever read downstream.
    const int prw = pos[b * 2 + 0], pcw = pos[b * 2 + 1];
    ushort_t* dst = yb + (size_t)(r0 * SGRID) * FD;
    #pragma unroll
    for (int jj = 0; jj < 4; ++jj) {
        const int e8 = (t + 256 * jj) * 8;
        const int cc = e8 >> 7, k = e8 & 127;
        const int rr = cc >> 5, c = cc & 31;
        const int grow = r0 + rr;
        if (grow >= prw - 3 && grow <= prw + 3 && c >= pcw - 3 && c <= pcw + 3)
            *(uint4*)(dst + e8) = *(const uint4*)&xt[cc * XSTR + k];
    }
}

// ---------------------------------------------------------------------------
// Meta kernel: per batch, m1 = elu(b1 + s0@Wn1), m2 = elu(b2 + m1@Ws2 + s1@Wn2).
// 128 blocks (XCD-swizzled) x 256 threads.
// ---------------------------------------------------------------------------
__global__ __launch_bounds__(256) void meta_kernel(
    const ushort_t* __restrict__ Ws,
    const ushort_t* __restrict__ Wn,
    const ushort_t* __restrict__ bs,
    const float* __restrict__ s0,
    const float* __restrict__ s1,
    float* __restrict__ m1g,             // f32, B x 128
    float* __restrict__ m2g)             // f32, B x 128
{
    const int b = (blockIdx.x & 7) * 16 + (blockIdx.x >> 3);
    const int t = threadIdx.x;
    const int cg = t & 31;
    const int c0 = cg * 4;
    const int kg = t >> 5;               // 0..7
    const int k0 = kg * 16;

    __shared__ float s0L[128], s1L[128], m1L[128];
    __shared__ float part[8][128];

    const ushort_t* Ws2 = Ws + FD * FD;
    const ushort_t* Wn2 = Wn + FD * FD;

    if (t < 128)      s0L[t] = s0[b * 128 + t];
    else              s1L[t - 128] = s1[b * 128 + (t - 128)];
    __syncthreads();

    // m1 partials.
    {
        float acc[4] = {0.f, 0.f, 0.f, 0.f};
        #pragma unroll
        for (int i = 0; i < 16; ++i) {
            const int k = k0 + i;
            float wv[4]; unpack4(*(const uint2*)(Wn + k * FD + c0), wv);
            const float sv = s0L[k];
            #pragma unroll
            for (int jq = 0; jq < 4; ++jq) acc[jq] += sv * wv[jq];
        }
        #pragma unroll
        for (int jq = 0; jq < 4; ++jq) part[kg][c0 + jq] = acc[jq];
    }
    __syncthreads();
    if (t < 128) {
        float a = bf2f(bs[t]);
        #pragma unroll
        for (int p = 0; p < 8; ++p) a += part[p][t];
        const float v = elu_fast(a);
        m1L[t] = v;
        m1g[b * 128 + t] = v;
    }
    __syncthreads();

    // m2 partials.
    {
        float acc[4] = {0.f, 0.f, 0.f, 0.f};
        #pragma unroll
        for (int i = 0; i < 16; ++i) {
            const int k = k0 + i;
            float wsv[4], wnv[4];
            unpack4(*(const uint2*)(Ws2 + k * FD + c0), wsv);
            unpack4(*(const uint2*)(Wn2 + k * FD + c0), wnv);
            const float mv = m1L[k], sv = s1L[k];
            #pragma unroll
            for (int jq = 0; jq < 4; ++jq) acc[jq] += mv * wsv[jq] + sv * wnv[jq];
        }
        #pragma unroll
        for (int jq = 0; jq < 4; ++jq) part[kg][c0 + jq] = acc[jq];
    }
    __syncthreads();
    if (t < 128) {
        float a = bf2f(bs[FD + t]);
        #pragma unroll
        for (int p = 0; p < 8; ++p) a += part[p][t];
        m2g[b * 128 + t] = elu_fast(a);
    }
}

// ---------------------------------------------------------------------------
// Head windows v3: 640 blocks x 512 threads. m1/m2 precomputed (meta_kernel).
// Phase 4b batches all 5 cells' partials into part5[16][640]. LDS ~54 KB.
// ---------------------------------------------------------------------------
__global__ __launch_bounds__(512) void head_window(
    const ushort_t* __restrict__ x1g,     // bf16, B x 1025 x 128
    const int* __restrict__ pos,
    const ushort_t* __restrict__ Ws,      // 3 x 128 x 128
    const ushort_t* __restrict__ Wn,
    const ushort_t* __restrict__ bs,      // 3 x 128
    const float* __restrict__ m1g,
    const float* __restrict__ m2g,
    float* __restrict__ stg)              // f32, B x 640
{
    const int xcd = blockIdx.x & 7;
    const int idx = blockIdx.x >> 3;       // 0..79
    const int b = xcd * 16 + idx / 5;
    const int g = idx % 5;
    const int t = threadIdx.x;
    const int f = t & 127;
    const int cg = t & 31;                 // col group: cols [cg*4, cg*4+4)
    const int c0 = cg * 4;
    const int kg = t >> 5;                 // 0..15, k range [kg*8, kg*8+8)
    const int k0 = kg * 8;

    // Diamond |dr|+|dc|<=2 around the plus cell P (13 cells).
    // idx:   0    1    2    3    4    5    6    7    8    9   10   11   12
    // off: (-2,0)(-1,-1)(-1,0)(-1,1)(0,-2)(0,-1)(0,0)(0,1)(0,2)(1,-1)(1,0)(1,1)(2,0)
    __shared__ float x1d[13][128];         // 6.5 KB
    __shared__ float x2d[5][128];
    __shared__ float aggd[5][128];
    __shared__ float m1L[128], m2L[128], agg3[128];
    __shared__ float part5[16][640];       // 40 KB

    const int OFFR[5] = {-1, 0, 1, 0, 0};
    const int OFFC[5] = {0, -1, 0, 1, 0};
    const int pr = pos[b * 2 + 0] + OFFR[g];
    const int pc = pos[b * 2 + 1] + OFFC[g];

    const ushort_t* Ws2 = Ws + FD * FD;
    const ushort_t* Wn2 = Wn + FD * FD;
    const ushort_t* Ws3 = Ws + 2 * FD * FD;
    const ushort_t* Wn3 = Wn + 2 * FD * FD;

    // ---- Phase 1: load m1/m2 + x1 diamond (uint4, zero out-of-grid) ----
    if (t < 128)      m1L[t] = m1g[b * 128 + t];
    else if (t < 256) m2L[t - 128] = m2g[b * 128 + (t - 128)];
    {
        const int D13R[13] = {-2,-1,-1,-1, 0, 0, 0, 0, 0, 1, 1, 1, 2};
        const int D13C[13] = { 0,-1, 0, 1,-2,-1, 0, 1, 2,-1, 0, 1, 0};
        if (t < 208) {                      // 13 cells x 16 uint4 groups
            const int ci = t >> 4, kq = (t & 15) * 8;
            const int r = pr + D13R[ci], c = pc + D13C[ci];
            float fv[8];
            if (r >= 0 && r < SGRID && c >= 0 && c < SGRID) {
                unpack8(*(const uint4*)(x1g + ((size_t)b * NTOT + r * SGRID + c) * FD + kq), fv);
            } else {
                #pragma unroll
                for (int jq = 0; jq < 8; ++jq) fv[jq] = 0.f;
            }
            #pragma unroll
            for (int jq = 0; jq < 8; ++jq) x1d[ci][kq + jq] = fv[jq];
        }
    }
    __syncthreads();

    // ---- Phase 4a: agg for 5 x2 cells (compile-time neighbor table) ----
    // C5 diamond idx: cell0=(-1,0)->2, cell1=(0,-1)->5, cell2=(0,0)->6,
    //                 cell3=(0,1)->7, cell4=(1,0)->10. Zero-padded x1d masks edges.
    if (t < 128) {
        const float mm = m1L[t];
        aggd[0][t] = x1d[0][t]  + x1d[6][t]  + x1d[1][t] + x1d[3][t]  + mm;
        aggd[1][t] = x1d[1][t]  + x1d[9][t]  + x1d[4][t] + x1d[6][t]  + mm;
        aggd[2][t] = x1d[2][t]  + x1d[10][t] + x1d[5][t] + x1d[7][t]  + mm;
        aggd[3][t] = x1d[3][t]  + x1d[11][t] + x1d[6][t] + x1d[8][t]  + mm;
        aggd[4][t] = x1d[6][t]  + x1d[12][t] + x1d[9][t] + x1d[11][t] + mm;
    }
    __syncthreads();

    // ---- Phase 4b: x2 at 5 cells, one shared K-pass, batched reduce ----
    {
        float acc[5][4];
        #pragma unroll
        for (int cc = 0; cc < 5; ++cc)
            #pragma unroll
            for (int jq = 0; jq < 4; ++jq) acc[cc][jq] = 0.f;
        #pragma unroll
        for (int i = 0; i < 8; ++i) {
            const int k = k0 + i;
            float wsv[4], wnv[4];
            unpack4(*(const uint2*)(Ws2 + k * FD + c0), wsv);
            unpack4(*(const uint2*)(Wn2 + k * FD + c0), wnv);
            const float xv0 = x1d[2][k],  av0 = aggd[0][k];
            const float xv1 = x1d[5][k],  av1 = aggd[1][k];
            const float xv2 = x1d[6][k],  av2 = aggd[2][k];
            const float xv3 = x1d[7][k],  av3 = aggd[3][k];
            const float xv4 = x1d[10][k], av4 = aggd[4][k];
            #pragma unroll
            for (int jq = 0; jq < 4; ++jq) {
                acc[0][jq] += xv0 * wsv[jq] + av0 * wnv[jq];
                acc[1][jq] += xv1 * wsv[jq] + av1 * wnv[jq];
                acc[2][jq] += xv2 * wsv[jq] + av2 * wnv[jq];
                acc[3][jq] += xv3 * wsv[jq] + av3 * wnv[jq];
                acc[4][jq] += xv4 * wsv[jq] + av4 * wnv[jq];
            }
        }
        #pragma unroll
        for (int cc = 0; cc < 5; ++cc)
            #pragma unroll
            for (int jq = 0; jq < 4; ++jq) part5[kg][cc * 128 + c0 + jq] = acc[cc][jq];
    }
    __syncthreads();
    for (int e = t; e < 640; e += 512) {
        const int cc = e >> 7, ff = e & 127;
        float a = bf2f(bs[FD + ff]);
        #pragma unroll
        for (int p = 0; p < 16; ++p) a += part5[p][e];
        x2d[cc][ff] = elu_fast(a);
    }
    __syncthreads();

    // ---- Phase 5a: agg3 at P (mask out-of-grid neighbors) ----
    if (t < 128) {
        float a = m2L[t];
        if (pr - 1 >= 0)    a += x2d[0][t];    // (-1,0)
        if (pr + 1 < SGRID) a += x2d[4][t];    // (1,0)
        if (pc - 1 >= 0)    a += x2d[1][t];    // (0,-1)
        if (pc + 1 < SGRID) a += x2d[3][t];    // (0,1)
        agg3[t] = a;
    }
    __syncthreads();

    // ---- Phase 5b: x3 at P; write st slice ----
    {
        float acc[4] = {0.f, 0.f, 0.f, 0.f};
        #pragma unroll
        for (int i = 0; i < 8; ++i) {
            const int k = k0 + i;
            float wsv[4], wnv[4];
            unpack4(*(const uint2*)(Ws3 + k * FD + c0), wsv);
            unpack4(*(const uint2*)(Wn3 + k * FD + c0), wnv);
            const float xv = x2d[2][k], av = agg3[k];
            #pragma unroll
            for (int jq = 0; jq < 4; ++jq) acc[jq] += xv * wsv[jq] + av * wnv[jq];
        }
        #pragma unroll
        for (int jq = 0; jq < 4; ++jq) part5[kg][c0 + jq] = acc[jq];
    }
    __syncthreads();
    if (t < 128) {
        const bool ig = (pr >= 0 && pr < SGRID && pc >= 0 && pc < SGRID);
        float a = bf2f(bs[2 * FD + f]);
        #pragma unroll
        for (int p = 0; p < 16; ++p) a += part5[p][f];
        stg[(size_t)b * 640 + g * 128 + f] = ig ? elu_fast(a) : 0.f;
    }
}

// ---------------------------------------------------------------------------
// Head MLP v2: 128 blocks (XCD-swizzled, 1 batch) x 512 threads = 8 waves.
// ---------------------------------------------------------------------------
__global__ __launch_bounds__(512) void head_mlp(
    const float* __restrict__ stg,        // f32, B x 640
    const int* __restrict__ amask,
    const ushort_t* __restrict__ Wd1, const ushort_t* __restrict__ bd1,
    const ushort_t* __restrict__ Wd2, const ushort_t* __restrict__ bd2,
    const ushort_t* __restrict__ Wd3, const ushort_t* __restrict__ bd3,
    const ushort_t* __restrict__ Wp1, const ushort_t* __restrict__ bp1,
    const ushort_t* __restrict__ Wp2, const ushort_t* __restrict__ bp2,
    const ushort_t* __restrict__ Wp3, const ushort_t* __restrict__ bp3,
    ushort_t* __restrict__ out)           // bf16, B x 19
{
    const int t = threadIdx.x;
    const int b = (blockIdx.x & 7) * 16 + (blockIdx.x >> 3);
    const int q = t >> 6;             // wave 0..7
    const int lane = t & 63;

    __shared__ float st[640];
    __shared__ float bufA[512];
    __shared__ float bufB[512];
    __shared__ float part[8][512];

    for (int e = t; e < 640; e += 512) st[e] = stg[(size_t)b * 640 + e];
    __syncthreads();

    // ---- L1: 640 -> 512 (80 k per wave; lane owns 8 cols) ----
    {
        float acc[8];
        #pragma unroll
        for (int p = 0; p < 8; ++p) acc[p] = 0.f;
        const int c0 = lane * 8;
        const int kb = q * 80;
        #pragma unroll 8
        for (int k = kb; k < kb + 80; ++k) {
            const float s = st[k];
            float fv[8]; unpack8(*(const uint4*)(Wd1 + (size_t)k * 512 + c0), fv);
            #pragma unroll
            for (int p = 0; p < 8; ++p) acc[p] += s * fv[p];
        }
        #pragma unroll
        for (int p = 0; p < 8; ++p) part[q][c0 + p] = acc[p];
        __syncthreads();
        {
            float a = bf2f(bd1[t]);
            #pragma unroll
            for (int p = 0; p < 8; ++p) a += part[p][t];
            bufA[t] = elu_fast(a);
        }
        __syncthreads();
    }
    // ---- L2: 512 -> 512 (64 k per wave) ----
    {
        float acc[8];
        #pragma unroll
        for (int p = 0; p < 8; ++p) acc[p] = 0.f;
        const int c0 = lane * 8;
        const int kb = q * 64;
        #pragma unroll 8
        for (int k = kb; k < kb + 64; ++k) {
            const float s = bufA[k];
            float fv[8]; unpack8(*(const uint4*)(Wd2 + (size_t)k * 512 + c0), fv);
            #pragma unroll
            for (int p = 0; p < 8; ++p) acc[p] += s * fv[p];
        }
        #pragma unroll
        for (int p = 0; p < 8; ++p) part[q][c0 + p] = acc[p];
        __syncthreads();
        {
            float a = bf2f(bd2[t]);
            #pragma unroll
            for (int p = 0; p < 8; ++p) a += part[p][t];
            bufB[t] = elu_fast(a);
        }
        __syncthreads();
    }
    // ---- L3: 512 -> 256 (64 k per wave; lane owns 4 cols) ----
    {
        float acc[4];
        #pragma unroll
        for (int p = 0; p < 4; ++p) acc[p] = 0.f;
        const int c0 = lane * 4;
        const int kb = q * 64;
        #pragma unroll 8
        for (int k = kb; k < kb + 64; ++k) {
            const float s = bufB[k];
            float fv[4]; unpack4(*(const uint2*)(Wd3 + (size_t)k * 256 + c0), fv);
            #pragma unroll
            for (int p = 0; p < 4; ++p) acc[p] += s * fv[p];
        }
        #pragma unroll
        for (int p = 0; p < 4; ++p) part[q][c0 + p] = acc[p];
        __syncthreads();
        if (t < 256) {
            float a = bf2f(bd3[t]);
            #pragma unroll
            for (int p = 0; p < 8; ++p) a += part[p][t];
            st[t] = elu_fast(a);
        }
        __syncthreads();
    }
    // ---- L4: 256 -> 256 (32 k per wave) ----
    {
        float acc[4];
        #pragma unroll
        for (int p = 0; p < 4; ++p) acc[p] = 0.f;
        const int c0 = lane * 4;
        const int kb = q * 32;
        #pragma unroll 8
        for (int k = kb; k < kb + 32; ++k) {
            const float s = st[k];
            float fv[4]; unpack4(*(const uint2*)(Wp1 + (size_t)k * 256 + c0), fv);
            #pragma unroll
            for (int p = 0; p < 4; ++p) acc[p] += s * fv[p];
        }
        #pragma unroll
        for (int p = 0; p < 4; ++p) part[q][c0 + p] = acc[p];
        __syncthreads();
        if (t < 256) {
            float a = bf2f(bp1[t]);
            #pragma unroll
            for (int p = 0; p < 8; ++p) a += part[p][t];
            bufA[t] = elu_fast(a);
        }
        __syncthreads();
    }
    // ---- L5: 256 -> 256 ----
    {
        float acc[4];
        #pragma unroll
        for (int p = 0; p < 4; ++p) acc[p] = 0.f;
        const int c0 = lane * 4;
        const int kb = q * 32;
        #pragma unroll 8
        for (int k = kb; k < kb + 32; ++k) {
            const float s = bufA[k];
            float fv[4]; unpack4(*(const uint2*)(Wp2 + (size_t)k * 256 + c0), fv);
            #pragma unroll
            for (int p = 0; p < 4; ++p) acc[p] += s * fv[p];
        }
        #pragma unroll
        for (int p = 0; p < 4; ++p) part[q][c0 + p] = acc[p];
        __syncthreads();
        if (t < 256) {
            float a = bf2f(bp2[t]);
            #pragma unroll
            for (int p = 0; p < 8; ++p) a += part[p][t];
            bufB[t] = elu_fast(a);
        }
        __syncthreads();
    }
    // ---- L6: 256 -> 19 + mask ----
    {
        float a = 0.f;
        const int kb = q * 32;
        if (lane < NACT) {
            #pragma unroll 8
            for (int k = kb; k < kb + 32; ++k)
                a += bufB[k] * bf2f(Wp3[(size_t)k * NACT + lane]);
            part[q][lane] = a;
        }
        __syncthreads();
        if (t < NACT) {
            float v = bf2f(bp3[t]);
            #pragma unroll
            for (int p = 0; p < 8; ++p) v += part[p][t];
            v += amask[b * NACT + t] ? 0.f : NEG_INF_F;
            v = fminf(fmaxf(v, -BF16_SAFE_F), BF16_SAFE_F);
            out[b * NACT + t] = f2bf(v);
        }
    }
}

extern "C" void kernel_launch(void* const* d_in, const int* in_sizes, int n_in,
                              void* d_out, int out_size, void* d_ws, size_t ws_size,
                              hipStream_t stream) {
    const ushort_t* gmap  = (const ushort_t*)d_in[0];
    const int*      pos   = (const int*)     d_in[1];
    const int*      amask = (const int*)     d_in[2];
    const ushort_t* Ws    = (const ushort_t*)d_in[3];
    const ushort_t* Wn    = (const ushort_t*)d_in[4];
    const ushort_t* bs    = (const ushort_t*)d_in[5];
    const ushort_t* Wd1   = (const ushort_t*)d_in[6];
    const ushort_t* bd1   = (const ushort_t*)d_in[7];
    const ushort_t* Wd2   = (const ushort_t*)d_in[8];
    const ushort_t* bd2   = (const ushort_t*)d_in[9];
    const ushort_t* Wd3   = (const ushort_t*)d_in[10];
    const ushort_t* bd3   = (const ushort_t*)d_in[11];
    const ushort_t* Wp1   = (const ushort_t*)d_in[12];
    const ushort_t* bp1   = (const ushort_t*)d_in[13];
    const ushort_t* Wp2   = (const ushort_t*)d_in[14];
    const ushort_t* bp2   = (const ushort_t*)d_in[15];
    const ushort_t* Wp3   = (const ushort_t*)d_in[16];
    const ushort_t* bp3   = (const ushort_t*)d_in[17];

    // Workspace: x1 (33.6 MB) + frags + s0/s1 + stg + m1/m2.
    ushort_t* x1 = (ushort_t*)d_ws;
    ushort_t* wfrag = x1 + (size_t)BATCH * NTOT * FD;
    float* s0s1 = (float*)(wfrag + 4096 * 8);
    float* s0 = s0s1;
    float* s1 = s0s1 + BATCH * FD;
    float* stg = s0s1 + 2 * BATCH * FD;
    float* m1g = stg + BATCH * 640;
    float* m2g = m1g + BATCH * FD;

    setup_kernel<<<32, 256, 0, stream>>>(Ws, Wn, wfrag, s0s1);

    gnn_layer1<<<16 * BATCH, 256, 0, stream>>>(gmap, x1, wfrag, bs, pos, s0, s1);

    meta_kernel<<<BATCH, 256, 0, stream>>>(Ws, Wn, bs, s0, s1, m1g, m2g);

    head_window<<<640, 512, 0, stream>>>(x1, pos, Ws, Wn, bs, m1g, m2g, stg);

    head_mlp<<<BATCH, 512, 0, stream>>>(stg, amask,
                                        Wd1, bd1, Wd2, bd2, Wd3, bd3,
                                        Wp1, bp1, Wp2, bp2, Wp3, bp3,
                                        (ushort_t*)d_out);
}